// Round 11
// baseline (490.375 us; speedup 1.0000x reference)
//
#include <hip/hip_runtime.h>
#include <math.h>

// B=32, N=32, P=64, Q=32, A=24, M=4, L=768, K=2

typedef __bf16 bf16x8 __attribute__((ext_vector_type(8)));
typedef float f32x4 __attribute__((ext_vector_type(4)));

#define MFMA __builtin_amdgcn_mfma_f32_16x16x32_bf16

// ---------------- prep: coalesced LDS-tile transposes ----------------
__global__ __launch_bounds__(256) void prep_kernel(
    const float* __restrict__ W5, const float* __restrict__ W6,
    const float* __restrict__ W7, const float* __restrict__ W8,
    const float* __restrict__ W9, const float* __restrict__ W10,
    const float* __restrict__ W11, const float* __restrict__ W12,
    const float* __restrict__ W13, const float* __restrict__ W14,
    __bf16* __restrict__ W5t_h, __bf16* __restrict__ W5t_l,
    __bf16* __restrict__ WsQT_h, __bf16* __restrict__ WsQT_l,
    __bf16* __restrict__ W6t_h, __bf16* __restrict__ W6t_l,
    __bf16* __restrict__ W1112T, __bf16* __restrict__ W78t,
    __bf16* __restrict__ W1314t) {
    __shared__ float T[32][33];
    int blk = blockIdx.x;
    int job, rel;
    if (blk < 576) { job = 0; rel = blk; }
    else if (blk < 1728) { job = 1; rel = blk - 576; }
    else if (blk < 3456) { job = 2; rel = blk - 1728; }
    else if (blk < 4608) { job = 3; rel = blk - 3456; }
    else if (blk < 5184) { job = 4; rel = blk - 4608; }
    else { job = 5; rel = blk - 5184; }
    int KT = (job == 2) ? 72 : (job == 5) ? 48 : 24;
    int Kdim = KT * 32;
    int ntile = rel / KT, ktile = rel - ntile * KT;
    int k0 = ktile * 32, n0 = ntile * 32;
    int t = threadIdx.x, tx = t & 31, ty = t >> 5;
#pragma unroll
    for (int s = 0; s < 4; s++) {
        int k = k0 + ty + 8 * s;
        int n = n0 + tx;
        float v;
        switch (job) {
            case 0: v = W5[(long)k * 768 + n]; break;
            case 1: v = (n < 768) ? W9[(long)k * 768 + n] : W10[(long)k * 768 + n - 768]; break;
            case 2: v = W6[(long)k * 768 + n]; break;
            case 3: v = (n < 768) ? W11[(long)k * 768 + n] : W12[(long)k * 768 + n - 768]; break;
            case 4: v = W7[(long)k * 768 + n] + W8[(long)k * 768 + n]; break;
            default: v = (k < 768) ? W13[(long)k * 768 + n] : W14[(long)(k - 768) * 768 + n]; break;
        }
        T[ty + 8 * s][tx] = v;
    }
    __syncthreads();
#pragma unroll
    for (int s = 0; s < 4; s++) {
        int n = n0 + ty + 8 * s;
        int k = k0 + tx;
        float v = T[tx][ty + 8 * s];
        long o = (long)n * Kdim + k;
        __bf16 h = (__bf16)v;
        switch (job) {
            case 0: W5t_h[o] = h; W5t_l[o] = (__bf16)(v - (float)h); break;
            case 1: WsQT_h[o] = h; WsQT_l[o] = (__bf16)(v - (float)h); break;
            case 2: W6t_h[o] = h; W6t_l[o] = (__bf16)(v - (float)h); break;
            case 3: W1112T[o] = h; break;
            case 4: W78t[o] = h; break;
            default: W1314t[o] = h; break;
        }
    }
}

// ---------------- cvt2 + rnorm fused (Ha + Hq in one launch) ----------------
__global__ __launch_bounds__(256) void cvt2n_kernel(
    const float* __restrict__ Ha, __bf16* __restrict__ Ha_h, __bf16* __restrict__ Ha_l,
    float* __restrict__ ra,
    const float* __restrict__ Hq, __bf16* __restrict__ Hq_h, __bf16* __restrict__ Hq_l,
    float* __restrict__ rq) {
    long row = blockIdx.x;
    const float* src; __bf16 *h, *l; float* rn;
    if (row < 3072) { src = Ha; h = Ha_h; l = Ha_l; rn = ra; }
    else { row -= 3072; src = Hq; h = Hq_h; l = Hq_l; rn = rq; }
    int t = threadIdx.x;
    const float* sr = src + row * 768;
    float ss = 0.f;
#pragma unroll
    for (int i = 0; i < 3; i++) {
        int idx = t + i * 256;
        float v = sr[idx];
        __bf16 hv = (__bf16)v;
        h[row * 768 + idx] = hv; l[row * 768 + idx] = (__bf16)(v - (float)hv);
        ss += v * v;
    }
    for (int o = 32; o; o >>= 1) ss += __shfl_xor(ss, o);
    __shared__ float red[4];
    if ((t & 63) == 0) red[t >> 6] = ss;
    __syncthreads();
    if (t == 0) rn[row] = 1.f / fmaxf(sqrtf(red[0] + red[1] + red[2] + red[3]), 1e-8f);
}

// ---------------- MFMA bf16x3 simmax with fused Hp row norms (pipelined) ----------------
__global__ __launch_bounds__(256) void simmax_kernel(
    const float* __restrict__ Hp,
    const __bf16* __restrict__ Ha_h, const __bf16* __restrict__ Ha_l,
    const __bf16* __restrict__ Hq_h, const __bf16* __restrict__ Hq_l,
    const float* __restrict__ ra, const float* __restrict__ rq,
    float* __restrict__ amax) {
    constexpr int LDT = 72;
    __shared__ alignas(16) __bf16 Ah[64 * LDT];
    __shared__ alignas(16) __bf16 Al[64 * LDT];
    __shared__ alignas(16) __bf16 Bh[128 * LDT];
    __shared__ alignas(16) __bf16 Bl[128 * LDT];
    __shared__ float rp_lds[64];
    __shared__ float wred[4][128];
    int b = blockIdx.x >> 5, n = blockIdx.x & 31;
    int t = threadIdx.x;
    const float* Ap = Hp + ((long)b * 2048 + n * 64) * 768;
    int srow = t >> 2, kq = (t & 3) << 4;
    int brow = t >> 1, kh = (t & 1) << 5;
    const __bf16 *Bsh, *Bsl;
    if (brow < 96) {
        Bsh = Ha_h + (long)b * 73728 + (long)brow * 768;
        Bsl = Ha_l + (long)b * 73728 + (long)brow * 768;
    } else {
        Bsh = Hq_h + (long)b * 24576 + (long)(brow - 96) * 768;
        Bsl = Hq_l + (long)b * 24576 + (long)(brow - 96) * 768;
    }
    int w = t >> 6, l = t & 63;
    int fr = l & 15, g = l >> 4;
    int wr = w << 4;
    f32x4 acc[8] = {};
    float ss = 0.f;
    const float* Arow = Ap + (long)srow * 768 + kq;
    float4 av0, av1, av2, av3;
    bf16x8 vbh0, vbh1, vbh2, vbh3, vbl0, vbl1, vbl2, vbl3;
    auto LOADS = [&](int k0) {
        av0 = *(const float4*)(Arow + k0 + 0);
        av1 = *(const float4*)(Arow + k0 + 4);
        av2 = *(const float4*)(Arow + k0 + 8);
        av3 = *(const float4*)(Arow + k0 + 12);
        vbh0 = *(const bf16x8*)(Bsh + k0 + kh);
        vbh1 = *(const bf16x8*)(Bsh + k0 + kh + 8);
        vbh2 = *(const bf16x8*)(Bsh + k0 + kh + 16);
        vbh3 = *(const bf16x8*)(Bsh + k0 + kh + 24);
        vbl0 = *(const bf16x8*)(Bsl + k0 + kh);
        vbl1 = *(const bf16x8*)(Bsl + k0 + kh + 8);
        vbl2 = *(const bf16x8*)(Bsl + k0 + kh + 16);
        vbl3 = *(const bf16x8*)(Bsl + k0 + kh + 24);
    };
    LOADS(0);
    for (int k0 = 0; k0 < 768; k0 += 64) {
        float va[16];
        *(float4*)(va + 0) = av0; *(float4*)(va + 4) = av1;
        *(float4*)(va + 8) = av2; *(float4*)(va + 12) = av3;
        bf16x8 h0, h1, l0, l1;
#pragma unroll
        for (int i = 0; i < 8; i++) {
            float v = va[i]; __bf16 hv = (__bf16)v;
            h0[i] = hv; l0[i] = (__bf16)(v - (float)hv); ss += v * v;
            v = va[8 + i]; hv = (__bf16)v;
            h1[i] = hv; l1[i] = (__bf16)(v - (float)hv); ss += v * v;
        }
        bf16x8 sbh0 = vbh0, sbh1 = vbh1, sbh2 = vbh2, sbh3 = vbh3;
        bf16x8 sbl0 = vbl0, sbl1 = vbl1, sbl2 = vbl2, sbl3 = vbl3;
        __syncthreads();
        *(bf16x8*)(&Ah[srow * LDT + kq]) = h0;
        *(bf16x8*)(&Ah[srow * LDT + kq + 8]) = h1;
        *(bf16x8*)(&Al[srow * LDT + kq]) = l0;
        *(bf16x8*)(&Al[srow * LDT + kq + 8]) = l1;
        *(bf16x8*)(&Bh[brow * LDT + kh]) = sbh0;
        *(bf16x8*)(&Bh[brow * LDT + kh + 8]) = sbh1;
        *(bf16x8*)(&Bh[brow * LDT + kh + 16]) = sbh2;
        *(bf16x8*)(&Bh[brow * LDT + kh + 24]) = sbh3;
        *(bf16x8*)(&Bl[brow * LDT + kh]) = sbl0;
        *(bf16x8*)(&Bl[brow * LDT + kh + 8]) = sbl1;
        *(bf16x8*)(&Bl[brow * LDT + kh + 16]) = sbl2;
        *(bf16x8*)(&Bl[brow * LDT + kh + 24]) = sbl3;
        if (k0 + 64 < 768) LOADS(k0 + 64);
        __syncthreads();
#pragma unroll
        for (int sub = 0; sub < 2; sub++) {
            int kb = sub * 32 + g * 8;
            bf16x8 fah = *(const bf16x8*)(&Ah[(wr + fr) * LDT + kb]);
            bf16x8 fal = *(const bf16x8*)(&Al[(wr + fr) * LDT + kb]);
#pragma unroll
            for (int c = 0; c < 8; c++) {
                bf16x8 fbh = *(const bf16x8*)(&Bh[(c * 16 + fr) * LDT + kb]);
                bf16x8 fbl = *(const bf16x8*)(&Bl[(c * 16 + fr) * LDT + kb]);
                acc[c] = MFMA(fah, fbh, acc[c], 0, 0, 0);
                acc[c] = MFMA(fah, fbl, acc[c], 0, 0, 0);
                acc[c] = MFMA(fal, fbh, acc[c], 0, 0, 0);
            }
        }
    }
    ss += __shfl_xor(ss, 1);
    ss += __shfl_xor(ss, 2);
    if ((t & 3) == 0) rp_lds[srow] = 1.f / fmaxf(sqrtf(ss), 1e-8f);
    __syncthreads();
    float rpv[4];
#pragma unroll
    for (int r = 0; r < 4; r++) rpv[r] = rp_lds[wr + g * 4 + r];
#pragma unroll
    for (int c = 0; c < 8; c++) {
        float mx = acc[c][0] * rpv[0];
        mx = fmaxf(mx, acc[c][1] * rpv[1]);
        mx = fmaxf(mx, acc[c][2] * rpv[2]);
        mx = fmaxf(mx, acc[c][3] * rpv[3]);
        mx = fmaxf(mx, __shfl_xor(mx, 16));
        mx = fmaxf(mx, __shfl_xor(mx, 32));
        if (g == 0) wred[w][c * 16 + fr] = mx;
    }
    __syncthreads();
    if (t < 128) {
        float m = fmaxf(fmaxf(wred[0][t], wred[1][t]), fmaxf(wred[2][t], wred[3][t]));
        float rc = (t < 96) ? ra[b * 96 + t] : rq[b * 32 + (t - 96)];
        amax[((long)b * 32 + n) * 128 + t] = m * rc;
    }
}

__global__ void score_top2_kernel(const float* __restrict__ amax, int* __restrict__ idx) {
    int b = blockIdx.x, t = threadIdx.x;
    __shared__ float sc[32];
    if (t < 32) {
        const float* am = amax + ((long)b * 32 + t) * 128;
        float sa = 0.f, sq = 0.f;
        for (int c = 0; c < 96; c++) sa += am[c];
        for (int c = 96; c < 128; c++) sq += am[c];
        sc[t] = sa / 24.f + sq / 32.f;
    }
    __syncthreads();
    if (t == 0) {
        float m0 = -1e30f; int i0 = 0;
        for (int n = 0; n < 32; n++) if (sc[n] > m0) { m0 = sc[n]; i0 = n; }
        float m1 = -1e30f; int i1 = 0;
        for (int n = 0; n < 32; n++) if (n != i0 && sc[n] > m1) { m1 = sc[n]; i1 = n; }
        idx[b * 2] = i0; idx[b * 2 + 1] = i1;
    }
}

__global__ void gather_kernel(const float* __restrict__ Hp, const int* __restrict__ idx,
                              __bf16* __restrict__ Hps_h, __bf16* __restrict__ Hps_l) {
    long i = (long)blockIdx.x * 256 + threadIdx.x;
    if (i >= (long)32 * 128 * 768) return;
    int l = (int)(i % 768);
    long r = i / 768;
    int x = (int)(r % 128); int b = (int)(r / 128);
    int k = x >> 6, p = x & 63;
    int n = idx[b * 2 + k];
    float v = Hp[((long)b * 2048 + n * 64 + p) * 768 + l];
    __bf16 h = (__bf16)v; Hps_h[i] = h; Hps_l[i] = (__bf16)(v - (float)h);
}

// ---------------- 128x128 bf16x3 MFMA GEMM body (K-step 32) ----------------
template <int OUT>
__device__ __forceinline__ void mg3b_body(
    const __bf16* __restrict__ Ah, const __bf16* __restrict__ Al, int Kdim,
    const __bf16* __restrict__ Wh, const __bf16* __restrict__ Wl,
    float* __restrict__ C, int ldc, __bf16* __restrict__ Ch, __bf16* __restrict__ Cl,
    int rowBase, int colBase, int t,
    __bf16* Ahs, __bf16* Als, __bf16* Bhs, __bf16* Bls) {
    constexpr int LDT = 40;
    int srow = t >> 1, skof = (t & 1) << 4;
    long aoff = (long)(rowBase + srow) * Kdim + skof;
    long woff = (long)(colBase + srow) * Kdim + skof;
    const __bf16* Aph = Ah + aoff;
    const __bf16* Apl = Al + aoff;
    const __bf16* Wph = Wh + woff;
    const __bf16* Wpl = Wl + woff;
    int w = t >> 6, l = t & 63;
    int wr = (w >> 1) << 6, wc = (w & 1) << 6;
    int fr = l & 15, g = l >> 4;
    f32x4 acc[4][4] = {};
    int nk = Kdim >> 5;
    bf16x8 rah0, rah1, ral0, ral1, rwh0, rwh1, rwl0, rwl1;
    auto LOADM = [&]() {
        rah0 = *(const bf16x8*)(Aph); rah1 = *(const bf16x8*)(Aph + 8);
        ral0 = *(const bf16x8*)(Apl); ral1 = *(const bf16x8*)(Apl + 8);
        rwh0 = *(const bf16x8*)(Wph); rwh1 = *(const bf16x8*)(Wph + 8);
        rwl0 = *(const bf16x8*)(Wpl); rwl1 = *(const bf16x8*)(Wpl + 8);
        Aph += 32; Apl += 32; Wph += 32; Wpl += 32;
    };
    LOADM();
    for (int ks = 0; ks < nk; ks++) {
        __syncthreads();
        *(bf16x8*)(&Ahs[srow * LDT + skof]) = rah0; *(bf16x8*)(&Ahs[srow * LDT + skof + 8]) = rah1;
        *(bf16x8*)(&Als[srow * LDT + skof]) = ral0; *(bf16x8*)(&Als[srow * LDT + skof + 8]) = ral1;
        *(bf16x8*)(&Bhs[srow * LDT + skof]) = rwh0; *(bf16x8*)(&Bhs[srow * LDT + skof + 8]) = rwh1;
        *(bf16x8*)(&Bls[srow * LDT + skof]) = rwl0; *(bf16x8*)(&Bls[srow * LDT + skof + 8]) = rwl1;
        if (ks + 1 < nk) LOADM();
        __syncthreads();
        int kb = g * 8;
        bf16x8 fah[4], fal[4], fbh[4], fbl[4];
#pragma unroll
        for (int i = 0; i < 4; i++) {
            fah[i] = *(const bf16x8*)(&Ahs[(wr + i * 16 + fr) * LDT + kb]);
            fal[i] = *(const bf16x8*)(&Als[(wr + i * 16 + fr) * LDT + kb]);
            fbh[i] = *(const bf16x8*)(&Bhs[(wc + i * 16 + fr) * LDT + kb]);
            fbl[i] = *(const bf16x8*)(&Bls[(wc + i * 16 + fr) * LDT + kb]);
        }
#pragma unroll
        for (int i = 0; i < 4; i++)
#pragma unroll
        for (int j = 0; j < 4; j++) {
            acc[i][j] = MFMA(fah[i], fbh[j], acc[i][j], 0, 0, 0);
            acc[i][j] = MFMA(fah[i], fbl[j], acc[i][j], 0, 0, 0);
            acc[i][j] = MFMA(fal[i], fbh[j], acc[i][j], 0, 0, 0);
        }
    }
#pragma unroll
    for (int fi = 0; fi < 4; fi++)
#pragma unroll
    for (int fj = 0; fj < 4; fj++)
#pragma unroll
    for (int r = 0; r < 4; r++) {
        int row = rowBase + wr + fi * 16 + g * 4 + r;
        int col = colBase + wc + fj * 16 + fr;
        float v = acc[fi][fj][r];
        long o = (long)row * ldc + col;
        if (OUT == 1) { C[o] = v; Ch[o] = (__bf16)v; }
        else {
            __bf16 h = (__bf16)v;
            Ch[o] = h; Cl[o] = (__bf16)(v - (float)h);
        }
    }
}

template <int OUT>
__global__ __launch_bounds__(256) void mgemm3b_kernel(
    const __bf16* __restrict__ Ah, const __bf16* __restrict__ Al, int Kdim,
    const __bf16* __restrict__ Wh, const __bf16* __restrict__ Wl,
    float* __restrict__ C, int ldc, __bf16* __restrict__ Ch, __bf16* __restrict__ Cl) {
    __shared__ alignas(16) __bf16 Ahs[128 * 40];
    __shared__ alignas(16) __bf16 Als[128 * 40];
    __shared__ alignas(16) __bf16 Bhs[128 * 40];
    __shared__ alignas(16) __bf16 Bls[128 * 40];
    mg3b_body<OUT>(Ah, Al, Kdim, Wh, Wl, C, ldc, Ch, Cl,
                   blockIdx.x << 7, blockIdx.y << 7, threadIdx.x, Ahs, Als, Bhs, Bls);
}

// batched 3-seg version (projection caches), OUT=2
struct PXSeg { const __bf16 *Ah, *Al, *Wh, *Wl; __bf16 *Ch, *Cl; int ldc, gx; };
struct PXArgs { PXSeg s[3]; };

__global__ __launch_bounds__(256) void projxb_kernel(PXArgs args) {
    __shared__ alignas(16) __bf16 Ahs[128 * 40];
    __shared__ alignas(16) __bf16 Als[128 * 40];
    __shared__ alignas(16) __bf16 Bhs[128 * 40];
    __shared__ alignas(16) __bf16 Bls[128 * 40];
    int bid = blockIdx.x;
    int seg = (bid < 144) ? 0 : (bid < 240) ? 1 : 2;
    int rel = bid - ((seg == 0) ? 0 : (seg == 1) ? 144 : 240);
    PXSeg sg = args.s[seg];
    int rowBase = (rel % sg.gx) << 7, colBase = (rel / sg.gx) << 7;
    mg3b_body<2>(sg.Ah, sg.Al, 768, sg.Wh, sg.Wl, nullptr, sg.ldc, sg.Ch, sg.Cl,
                 rowBase, colBase, threadIdx.x, Ahs, Als, Bhs, Bls);
}

// ---------------- 128x128 plain bf16 MFMA GEMM body (K-step 64) ----------------
__device__ __forceinline__ void mgb_body(
    const __bf16* __restrict__ A, int Kdim, const __bf16* __restrict__ Wt,
    __bf16* __restrict__ Cb, int ldc,
    int rowBase, int colBase, int t, __bf16* As, __bf16* Bs) {
    constexpr int LDT = 72;
    int srow = t >> 1, skof = (t & 1) << 5;
    const __bf16* Ap = A + (long)(rowBase + srow) * Kdim + skof;
    const __bf16* Wp = Wt + (long)(colBase + srow) * Kdim + skof;
    int w = t >> 6, l = t & 63;
    int wr = (w >> 1) << 6, wc = (w & 1) << 6;
    int fr = l & 15, g = l >> 4;
    f32x4 acc[4][4] = {};
    int nk = Kdim >> 6;
    bf16x8 ra0, ra1, ra2, ra3, rw0, rw1, rw2, rw3;
    auto LOADM = [&]() {
        ra0 = *(const bf16x8*)(Ap);      ra1 = *(const bf16x8*)(Ap + 8);
        ra2 = *(const bf16x8*)(Ap + 16); ra3 = *(const bf16x8*)(Ap + 24);
        rw0 = *(const bf16x8*)(Wp);      rw1 = *(const bf16x8*)(Wp + 8);
        rw2 = *(const bf16x8*)(Wp + 16); rw3 = *(const bf16x8*)(Wp + 24);
        Ap += 64; Wp += 64;
    };
    LOADM();
    for (int ks = 0; ks < nk; ks++) {
        __syncthreads();
        *(bf16x8*)(&As[srow * LDT + skof]) = ra0;      *(bf16x8*)(&As[srow * LDT + skof + 8]) = ra1;
        *(bf16x8*)(&As[srow * LDT + skof + 16]) = ra2; *(bf16x8*)(&As[srow * LDT + skof + 24]) = ra3;
        *(bf16x8*)(&Bs[srow * LDT + skof]) = rw0;      *(bf16x8*)(&Bs[srow * LDT + skof + 8]) = rw1;
        *(bf16x8*)(&Bs[srow * LDT + skof + 16]) = rw2; *(bf16x8*)(&Bs[srow * LDT + skof + 24]) = rw3;
        if (ks + 1 < nk) LOADM();
        __syncthreads();
#pragma unroll
        for (int sub = 0; sub < 2; sub++) {
            int kb = sub * 32 + g * 8;
            bf16x8 fa[4], fb[4];
#pragma unroll
            for (int i = 0; i < 4; i++) {
                fa[i] = *(const bf16x8*)(&As[(wr + i * 16 + fr) * LDT + kb]);
                fb[i] = *(const bf16x8*)(&Bs[(wc + i * 16 + fr) * LDT + kb]);
            }
#pragma unroll
            for (int i = 0; i < 4; i++)
#pragma unroll
            for (int j = 0; j < 4; j++)
                acc[i][j] = MFMA(fa[i], fb[j], acc[i][j], 0, 0, 0);
        }
    }
#pragma unroll
    for (int fi = 0; fi < 4; fi++)
#pragma unroll
    for (int fj = 0; fj < 4; fj++)
#pragma unroll
    for (int r = 0; r < 4; r++) {
        int row = rowBase + wr + fi * 16 + g * 4 + r;
        int col = colBase + wc + fj * 16 + fr;
        Cb[(long)row * ldc + col] = (__bf16)acc[fi][fj][r];
    }
}

__global__ __launch_bounds__(256) void mgemmb_kernel(
    const __bf16* __restrict__ A, int Kdim, const __bf16* __restrict__ Wt,
    __bf16* __restrict__ Cb, int ldc) {
    __shared__ alignas(16) __bf16 As[128 * 72];
    __shared__ alignas(16) __bf16 Bs[128 * 72];
    mgb_body(A, Kdim, Wt, Cb, ldc, blockIdx.x << 7, blockIdx.y << 7, threadIdx.x, As, Bs);
}

struct PPSeg { const __bf16 *A, *Wt; __bf16* Cb; int ldc, gx; };
struct PPArgs { PPSeg s[2]; };

__global__ __launch_bounds__(256) void projpb_kernel(PPArgs args) {
    __shared__ alignas(16) __bf16 As[128 * 72];
    __shared__ alignas(16) __bf16 Bs[128 * 72];
    int bid = blockIdx.x;
    int seg = (bid < 96) ? 0 : 1;
    int rel = bid - ((seg == 0) ? 0 : 96);
    PPSeg sg = args.s[seg];
    int rowBase = (rel % sg.gx) << 7, colBase = (rel / sg.gx) << 7;
    mgb_body(sg.A, 768, sg.Wt, sg.Cb, sg.ldc, rowBase, colBase, threadIdx.x, As, Bs);
}

// ---------------- bf16 MFMA GEMM 64x64 (gating, small M) ----------------
template <int BIASF, int BOUT>
__global__ __launch_bounds__(256) void mgemm_kernel(
    const __bf16* __restrict__ A, int Kdim, int Mtot,
    const __bf16* __restrict__ Wt, const float* __restrict__ bias,
    float* __restrict__ C, int ldc, __bf16* __restrict__ Cb) {
    constexpr int LDT = 80;
    __shared__ alignas(16) __bf16 As[64 * LDT];
    __shared__ alignas(16) __bf16 Bs[64 * LDT];
    int t = threadIdx.x;
    int rowBase = blockIdx.x << 6, colBase = blockIdx.y << 6;
    int srow = t >> 2, skof = (t & 3) << 3;
    int arow = rowBase + srow;
    bool aok = arow < Mtot;
    const __bf16* Ap = A + (long)(aok ? arow : rowBase) * Kdim + skof;
    const __bf16* Wp = Wt + (long)(colBase + srow) * Kdim + skof;
    int w = t >> 6, l = t & 63;
    int wr = (w >> 1) << 5, wc = (w & 1) << 5;
    int fr = l & 15, g = l >> 4;
    f32x4 acc[2][2] = {};
    int nk = Kdim >> 6;
    bf16x8 a0, a1, w0, w1;
    auto LOADM = [&]() {
        a0 = *(const bf16x8*)(Ap); a1 = *(const bf16x8*)(Ap + 32);
        w0 = *(const bf16x8*)(Wp); w1 = *(const bf16x8*)(Wp + 32);
        Ap += 64; Wp += 64;
    };
    LOADM();
    for (int ks = 0; ks < nk; ks++) {
        __syncthreads();
        *(bf16x8*)(&As[srow * LDT + skof]) = a0;
        *(bf16x8*)(&As[srow * LDT + 32 + skof]) = a1;
        *(bf16x8*)(&Bs[srow * LDT + skof]) = w0;
        *(bf16x8*)(&Bs[srow * LDT + 32 + skof]) = w1;
        if (ks + 1 < nk) LOADM();
        __syncthreads();
#pragma unroll
        for (int sub = 0; sub < 2; sub++) {
            int ko = sub * 32 + g * 8;
            bf16x8 fa0 = *(const bf16x8*)(&As[(wr + fr) * LDT + ko]);
            bf16x8 fa1 = *(const bf16x8*)(&As[(wr + 16 + fr) * LDT + ko]);
            bf16x8 fb0 = *(const bf16x8*)(&Bs[(wc + fr) * LDT + ko]);
            bf16x8 fb1 = *(const bf16x8*)(&Bs[(wc + 16 + fr) * LDT + ko]);
            acc[0][0] = MFMA(fa0, fb0, acc[0][0], 0, 0, 0);
            acc[0][1] = MFMA(fa0, fb1, acc[0][1], 0, 0, 0);
            acc[1][0] = MFMA(fa1, fb0, acc[1][0], 0, 0, 0);
            acc[1][1] = MFMA(fa1, fb1, acc[1][1], 0, 0, 0);
        }
    }
#pragma unroll
    for (int fi = 0; fi < 2; fi++)
#pragma unroll
    for (int fj = 0; fj < 2; fj++)
#pragma unroll
    for (int r = 0; r < 4; r++) {
        int row = rowBase + wr + fi * 16 + g * 4 + r;
        int col = colBase + wc + fj * 16 + (l & 15);
        if (row < Mtot) {
            float v = acc[fi][fj][r];
            if (BIASF) v += bias[col];
            if (BOUT == 0) C[(long)row * ldc + col] = v;
            else Cb[(long)row * ldc + col] = (__bf16)v;
        }
    }
}

// ---------------- mgemm + fused sigmoid-gate epilogue (64x64) ----------------
__global__ __launch_bounds__(256) void mgemm_gate_kernel(
    const __bf16* __restrict__ A, const __bf16* __restrict__ Wt, const float* __restrict__ bias,
    const float* __restrict__ HaF, const float* __restrict__ barF,
    __bf16* __restrict__ Ho_h, __bf16* __restrict__ Ho_l) {
    constexpr int LDT = 80;
    constexpr int Kdim = 768;
    __shared__ alignas(16) __bf16 As[64 * LDT];
    __shared__ alignas(16) __bf16 Bs[64 * LDT];
    int t = threadIdx.x;
    int rowBase = blockIdx.x << 6, colBase = blockIdx.y << 6;
    int srow = t >> 2, skof = (t & 3) << 3;
    const __bf16* Ap = A + (long)(rowBase + srow) * Kdim + skof;
    const __bf16* Wp = Wt + (long)(colBase + srow) * Kdim + skof;
    int w = t >> 6, l = t & 63;
    int wr = (w >> 1) << 5, wc = (w & 1) << 5;
    int fr = l & 15, g = l >> 4;
    f32x4 acc[2][2] = {};
    bf16x8 a0, a1, w0, w1;
    auto LOADM = [&]() {
        a0 = *(const bf16x8*)(Ap); a1 = *(const bf16x8*)(Ap + 32);
        w0 = *(const bf16x8*)(Wp); w1 = *(const bf16x8*)(Wp + 32);
        Ap += 64; Wp += 64;
    };
    LOADM();
    for (int ks = 0; ks < 12; ks++) {
        __syncthreads();
        *(bf16x8*)(&As[srow * LDT + skof]) = a0;
        *(bf16x8*)(&As[srow * LDT + 32 + skof]) = a1;
        *(bf16x8*)(&Bs[srow * LDT + skof]) = w0;
        *(bf16x8*)(&Bs[srow * LDT + 32 + skof]) = w1;
        if (ks + 1 < 12) LOADM();
        __syncthreads();
#pragma unroll
        for (int sub = 0; sub < 2; sub++) {
            int ko = sub * 32 + g * 8;
            bf16x8 fa0 = *(const bf16x8*)(&As[(wr + fr) * LDT + ko]);
            bf16x8 fa1 = *(const bf16x8*)(&As[(wr + 16 + fr) * LDT + ko]);
            bf16x8 fb0 = *(const bf16x8*)(&Bs[(wc + fr) * LDT + ko]);
            bf16x8 fb1 = *(const bf16x8*)(&Bs[(wc + 16 + fr) * LDT + ko]);
            acc[0][0] = MFMA(fa0, fb0, acc[0][0], 0, 0, 0);
            acc[0][1] = MFMA(fa0, fb1, acc[0][1], 0, 0, 0);
            acc[1][0] = MFMA(fa1, fb0, acc[1][0], 0, 0, 0);
            acc[1][1] = MFMA(fa1, fb1, acc[1][1], 0, 0, 0);
        }
    }
#pragma unroll
    for (int fi = 0; fi < 2; fi++)
#pragma unroll
    for (int fj = 0; fj < 2; fj++)
#pragma unroll
    for (int r = 0; r < 4; r++) {
        int row = rowBase + wr + fi * 16 + g * 4 + r;
        int col = colBase + wc + fj * 16 + (l & 15);
        float v = acc[fi][fj][r] + bias[col];
        float gt = 1.f / (1.f + expf(-v));
        long o = (long)row * 768 + col;
        float hv = gt * HaF[o] + (1.f - gt) * barF[o];
        __bf16 hb = (__bf16)hv;
        Ho_h[o] = hb; Ho_l[o] = (__bf16)(hv - (float)hb);
    }
}

// ---------------- fused QK+softmax+hats (stage 2, X=Y=24) ----------------
struct QHSeg {
    const __bf16 *GLh, *GLl, *HYh, *HYl;
    __bf16 *outH, *outL;
    long glB, hyB, oB;
};
struct QHArgs { QHSeg s[12]; };

__global__ __launch_bounds__(256) void qkh_kernel(QHArgs args) {
    constexpr int X = 24, Y = 24, XR = 32, YR = 32, LDT = 72;
    constexpr int YRp = YR + 1;
    constexpr int Ck = 32, Cpad = 40;
    constexpr int scPad = (XR * YRp * 4 + 15) & ~15;
    constexpr int btSz = 2 * 64 * Cpad * 2;
    constexpr int gOff = btSz;
    __shared__ alignas(16) char POOL[18432];
    __bf16* Ah_ = (__bf16*)POOL;
    __bf16* Al_ = Ah_ + XR * LDT;
    int seg = blockIdx.x >> 5, b = blockIdx.x & 31;
    QHSeg sg = args.s[seg];
    int t = threadIdx.x;
    __bf16* Bh_ = Ah_ + 2 * XR * LDT;
    __bf16* Bl_ = Bh_ + YR * LDT;
    float* sc   = (float*)POOL;
    float* invr = (float*)(POOL + scPad);
    __bf16* Bth = (__bf16*)POOL;
    __bf16* Btl = Bth + 64 * Cpad;
    __bf16* Gh  = (__bf16*)(POOL + gOff);
    __bf16* Gl  = Gh + XR * Cpad;
    int w = t >> 6, l = t & 63, fr = l & 15, g = l >> 4;
    const __bf16* GLbh = sg.GLh + (long)b * sg.glB;
    const __bf16* GLbl = sg.GLl + (long)b * sg.glB;
    const __bf16* HYbh = sg.HYh + (long)b * sg.hyB;
    const __bf16* HYbl = sg.HYl + (long)b * sg.hyB;
    f32x4 acc;
#pragma unroll
    for (int r = 0; r < 4; r++) acc[r] = 0.f;
    for (int k0 = 0; k0 < 768; k0 += 64) {
        __syncthreads();
        for (int v = t; v < (XR + YR) * 16; v += 256) {
            int row = v >> 4, sub = v & 15, hl = sub >> 3, k8 = (sub & 7) << 3;
            bf16x8 val = {};
            __bf16* dst;
            if (row < XR) {
                if (row < X)
                    val = *(const bf16x8*)((hl ? GLbl : GLbh) + (long)row * 768 + k0 + k8);
                dst = (hl ? Al_ : Ah_) + row * LDT + k8;
            } else {
                int r2 = row - XR;
                if (r2 < Y)
                    val = *(const bf16x8*)((hl ? HYbl : HYbh) + (long)r2 * 768 + k0 + k8);
                dst = (hl ? Bl_ : Bh_) + r2 * LDT + k8;
            }
            *(bf16x8*)dst = val;
        }
        __syncthreads();
#pragma unroll
        for (int sub = 0; sub < 2; sub++) {
            int kb = sub * 32 + g * 8;
            int xm = w >> 1, yc = w & 1;
            bf16x8 fah = *(const bf16x8*)(&Ah_[(xm * 16 + fr) * LDT + kb]);
            bf16x8 fal = *(const bf16x8*)(&Al_[(xm * 16 + fr) * LDT + kb]);
            bf16x8 fbh = *(const bf16x8*)(&Bh_[(yc * 16 + fr) * LDT + kb]);
            bf16x8 fbl = *(const bf16x8*)(&Bl_[(yc * 16 + fr) * LDT + kb]);
            acc = MFMA(fah, fbh, acc, 0, 0, 0);
            acc = MFMA(fah, fbl, acc, 0, 0, 0);
            acc = MFMA(fal, fbh, acc, 0, 0, 0);
        }
    }
    __syncthreads();
    {
        int xm = w >> 1, yc = w & 1;
#pragma unroll
        for (int r = 0; r < 4; r++)
            sc[(xm * 16 + g * 4 + r) * YRp + yc * 16 + fr] = acc[r];
    }
    __syncthreads();
    {
        constexpr int TPR = 256 / XR;
        int row = t / TPR, sub = t & (TPR - 1);
        if (row < X) {
            float* sr = sc + row * YRp;
            float m = -1e30f;
            for (int c = sub; c < Y; c += TPR) m = fmaxf(m, sr[c]);
#pragma unroll
            for (int o = 1; o < TPR; o <<= 1) m = fmaxf(m, __shfl_xor(m, o));
            float s = 0.f;
            for (int c = sub; c < Y; c += TPR) { float e = expf(sr[c] - m); sr[c] = e; s += e; }
#pragma unroll
            for (int o = 1; o < TPR; o <<= 1) s += __shfl_xor(s, o);
            if (sub == 0) invr[row] = 1.f / s;
        }
    }
    __syncthreads();
    for (int idx = t; idx < XR * Ck; idx += 256) {
        int r = idx >> 5, c = idx & 31;
        float v = (r < X && c < Y) ? sc[r * YRp + c] * invr[r] : 0.f;
        __bf16 h = (__bf16)v;
        Gh[r * Cpad + c] = h; Gl[r * Cpad + c] = (__bf16)(v - (float)h);
    }
    int bl = t & 63, bc0 = t >> 6;
    for (int n0 = 0; n0 < 768; n0 += 64) {
        __syncthreads();
        for (int c = bc0; c < Ck; c += 4) {
            __bf16 hv = (__bf16)0.f, lv = (__bf16)0.f;
            if (c < Y) { hv = HYbh[(long)c * 768 + n0 + bl]; lv = HYbl[(long)c * 768 + n0 + bl]; }
            Bth[bl * Cpad + c] = hv; Btl[bl * Cpad + c] = lv;
        }
        __syncthreads();
        bf16x8 bh = *(const bf16x8*)(&Bth[(w * 16 + fr) * Cpad + g * 8]);
        bf16x8 blv = *(const bf16x8*)(&Btl[(w * 16 + fr) * Cpad + g * 8]);
        f32x4 a2[2] = {};
#pragma unroll
        for (int m = 0; m < 2; m++) {
            bf16x8 gah = *(const bf16x8*)(&Gh[(m * 16 + fr) * Cpad + g * 8]);
            bf16x8 gal = *(const bf16x8*)(&Gl[(m * 16 + fr) * Cpad + g * 8]);
            a2[m] = MFMA(gah, bh, a2[m], 0, 0, 0);
            a2[m] = MFMA(gal, bh, a2[m], 0, 0, 0);
            a2[m] = MFMA(gah, blv, a2[m], 0, 0, 0);
        }
#pragma unroll
        for (int m = 0; m < 2; m++)
#pragma unroll
        for (int r = 0; r < 4; r++) {
            int row = m * 16 + g * 4 + r;
            if (row < X) {
                float v = fmaxf(a2[m][r], 0.f);
                __bf16 h = (__bf16)v;
                long o = (long)b * sg.oB + (long)row * 2304 + n0 + w * 16 + fr;
                sg.outH[o] = h; sg.outL[o] = (__bf16)(v - (float)h);
            }
        }
    }
}

// ---------------- fused QK+softmax+colmax S (match stage) ----------------
struct QSSeg {
    const __bf16 *GLh, *GLl, *HYh, *HYl, *B;
    float* outF; __bf16* outH;
    long glB, hyB, bB;
    int ldGL, ldHY, ldB, shape;
};
struct QSArgs { QSSeg s[18]; };

template <int X, int Y>
__device__ __forceinline__ void qks_impl(char* POOL, const QSSeg& sg, int b, int t) {
    constexpr int XR = (X + 15) & ~15;
    constexpr int YR = (Y + 15) & ~15;
    constexpr int LDT = 72;
    constexpr int YC = YR / 16;
    constexpr int F = (XR / 16) * YC;
    constexpr int F4 = F / 4;
    constexpr int YRp = YR + 1;
    constexpr int Rk = XR;
    constexpr int Ck = (Y + 31) & ~31;
    constexpr int Cpad = Ck + 8;
    constexpr int NM = Rk / 16;
    constexpr int scPad = (XR * YRp * 4 + 15) & ~15;
    constexpr int invrEnd = scPad + 512;
    constexpr int btSz = 64 * Cpad * 2;
    constexpr int gOff = ((invrEnd > btSz ? invrEnd : btSz) + 15) & ~15;
    static_assert(gOff + 2 * Rk * Cpad * 2 <= 46080, "pool overflow");
    __bf16* Ah_ = (__bf16*)POOL;
    __bf16* Al_ = Ah_ + XR * LDT;
    __bf16* Bh_ = Ah_ + 2 * XR * LDT;
    __bf16* Bl_ = Bh_ + YR * LDT;
    float* sc   = (float*)POOL;
    float* invr = (float*)(POOL + scPad);
    __bf16* Bt  = (__bf16*)POOL;
    __bf16* Gh  = (__bf16*)(POOL + gOff);
    __bf16* Gl  = Gh + Rk * Cpad;
    int w = t >> 6, l = t & 63, fr = l & 15, g = l >> 4;
    const __bf16* GLbh = sg.GLh + (long)b * sg.glB;
    const __bf16* GLbl = sg.GLl + (long)b * sg.glB;
    const __bf16* HYbh = sg.HYh + (long)b * sg.hyB;
    const __bf16* HYbl = sg.HYl + (long)b * sg.hyB;
    f32x4 acc[F4] = {};
    for (int k0 = 0; k0 < 768; k0 += 64) {
        __syncthreads();
        for (int v = t; v < (XR + YR) * 16; v += 256) {
            int row = v >> 4, sub = v & 15, hl = sub >> 3, k8 = (sub & 7) << 3;
            bf16x8 val = {};
            __bf16* dst;
            if (row < XR) {
                if (row < X)
                    val = *(const bf16x8*)((hl ? GLbl : GLbh) + (long)row * sg.ldGL + k0 + k8);
                dst = (hl ? Al_ : Ah_) + row * LDT + k8;
            } else {
                int r2 = row - XR;
                if (r2 < Y)
                    val = *(const bf16x8*)((hl ? HYbl : HYbh) + (long)r2 * sg.ldHY + k0 + k8);
                dst = (hl ? Bl_ : Bh_) + r2 * LDT + k8;
            }
            *(bf16x8*)dst = val;
        }
        __syncthreads();
#pragma unroll
        for (int sub = 0; sub < 2; sub++) {
            int kb = sub * 32 + g * 8;
#pragma unroll
            for (int ff = 0; ff < F4; ff++) {
                int fidx = w + ff * 4;
                int xm = fidx / YC, yc = fidx % YC;
                bf16x8 fah = *(const bf16x8*)(&Ah_[(xm * 16 + fr) * LDT + kb]);
                bf16x8 fal = *(const bf16x8*)(&Al_[(xm * 16 + fr) * LDT + kb]);
                bf16x8 fbh = *(const bf16x8*)(&Bh_[(yc * 16 + fr) * LDT + kb]);
                bf16x8 fbl = *(const bf16x8*)(&Bl_[(yc * 16 + fr) * LDT + kb]);
                acc[ff] = MFMA(fah, fbh, acc[ff], 0, 0, 0);
                acc[ff] = MFMA(fah, fbl, acc[ff], 0, 0, 0);
                acc[ff] = MFMA(fal, fbh, acc[ff], 0, 0, 0);
            }
        }
    }
    __syncthreads();
#pragma unroll
    for (int ff = 0; ff < F4; ff++) {
        int fidx = w + ff * 4;
        int xm = fidx / YC, yc = fidx % YC;
#pragma unroll
        for (int r = 0; r < 4; r++)
            sc[(xm * 16 + g * 4 + r) * YRp + yc * 16 + fr] = acc[ff][r];
    }
    __syncthreads();
    {
        constexpr int TPR = 256 / XR;
        int row = t / TPR, sub = t & (TPR - 1);
        if (row < X) {
            float* sr = sc + row * YRp;
            float m = -1e30f;
            for (int c = sub; c < Y; c += TPR) m = fmaxf(m, sr[c]);
#pragma unroll
            for (int o = 1; o < TPR; o <<= 1) m = fmaxf(m, __shfl_xor(m, o));
            float s = 0.f;
            for (int c = sub; c < Y; c += TPR) { float e = expf(sr[c] - m); sr[c] = e; s += e; }
#pragma unroll
            for (int o = 1; o < TPR; o <<= 1) s += __shfl_xor(s, o);
            if (sub == 0) invr[row] = 1.f / s;
        }
    }
    __syncthreads();
    for (int idx = t; idx < Rk * Ck; idx += 256) {
        int r = idx / Ck, c = idx - r * Ck;
        float v = (r < X && c < Y) ? sc[r * YRp + c] * invr[r] : 0.f;
        __bf16 h = (__bf16)v;
        Gh[r * Cpad + c] = h; Gl[r * Cpad + c] = (__bf16)(v - (float)h);
    }
    const __bf16* Bb = sg.B + (long)b * sg.bB;
    int bl = t & 63, bc0 = t >> 6;
    for (int n0 = 0; n0 < 768; n0 += 64) {
        __syncthreads();
        for (int c = bc0; c < Ck; c += 4) {
            __bf16 hv = (__bf16)0.f;
            if (c < Y) hv = Bb[(long)c * sg.ldB + n0 + bl];
            Bt[bl * Cpad + c] = hv;
        }
        __syncthreads();
        f32x4 a2[NM] = {};
#pragma unroll
        for (int ks = 0; ks < Ck; ks += 32) {
            bf16x8 bh = *(const bf16x8*)(&Bt[(w * 16 + fr) * Cpad + ks + g * 8]);
#pragma unroll
            for (int m = 0; m < NM; m++) {
                bf16x8 gah = *(const bf16x8*)(&Gh[(m * 16 + fr) * Cpad + ks + g * 8]);
                bf16x8 gal = *(const bf16x8*)(&Gl[(m * 16 + fr) * Cpad + ks + g * 8]);
                a2[m] = MFMA(gah, bh, a2[m], 0, 0, 0);
                a2[m] = MFMA(gal, bh, a2[m], 0, 0, 0);
            }
        }
        float mx = 0.f;
#pragma unroll
        for (int m = 0; m < NM; m++)
#pragma unroll
            for (int r = 0; r < 4; r++) mx = fmaxf(mx, a2[m][r]);
        mx = fmaxf(mx, __shfl_xor(mx, 16));
        mx = fmaxf(mx, __shfl_xor(mx, 32));
        if (g == 0) {
            int col = n0 + w * 16 + fr;
            sg.outF[(long)b * 1536 + col] = mx;
            sg.outH[(long)b * 1536 + col] = (__bf16)mx;
        }
    }
}

__global__ __launch_bounds__(256) void qks_kernel(QSArgs args) {
    __shared__ alignas(16) char POOL[46080];
    int seg = blockIdx.x >> 5, b = blockIdx.x & 31;
    QSSeg sg = args.s[seg];
    int t = threadIdx.x;
    switch (sg.shape) {
        case 1: qks_impl<128, 32>(POOL, sg, b, t); break;
        case 2: qks_impl<128, 24>(POOL, sg, b, t); break;
        case 3: qks_impl<32, 24>(POOL, sg, b, t); break;
        case 4: qks_impl<24, 32>(POOL, sg, b, t); break;
        case 5: qks_impl<32, 128>(POOL, sg, b, t); break;
        default: qks_impl<24, 128>(POOL, sg, b, t); break;
    }
}

// ---------------- logits + log_softmax fused ----------------
__global__ __launch_bounds__(256) void logits_lsm_kernel(
    const float* __restrict__ S, const float* __restrict__ gts,
    const float* __restrict__ V, float* __restrict__ out) {
    int b = blockIdx.x;
    int t = threadIdx.x, i = t >> 6, lane = t & 63;
    int ms[3] = {0, 1 + i, 5 + i};
    float p = 0.f;
    for (int k = 0; k < 3; k++) {
        int m = ms[k];
        const float* Sr = S + (long)m * 49152 + (long)b * 1536;
        const float* gr = gts + ((long)m * 32 + b) * 768;
        const float* Vr = V + k * 768;
        for (int l = lane; l < 768; l += 64) {
            float g = 1.f / (1.f + expf(-gr[l]));
            p += (g * Sr[l] + (1.f - g) * Sr[768 + l]) * Vr[l];
        }
    }
    for (int o = 32; o; o >>= 1) p += __shfl_xor(p, o);
    __shared__ float lgs[4];
    if (lane == 0) lgs[i] = p;
    __syncthreads();
    if (t == 0) {
        float x0 = lgs[0], x1 = lgs[1], x2 = lgs[2], x3 = lgs[3];
        float m = fmaxf(fmaxf(x0, x1), fmaxf(x2, x3));
        float s = expf(x0 - m) + expf(x1 - m) + expf(x2 - m) + expf(x3 - m);
        float ls = m + logf(s);
        out[b * 4 + 0] = x0 - ls; out[b * 4 + 1] = x1 - ls;
        out[b * 4 + 2] = x2 - ls; out[b * 4 + 3] = x3 - ls;
    }
}

// ---------------- host ----------------
extern "C" void kernel_launch(void* const* d_in, const int* in_sizes, int n_in,
                              void* d_out, int out_size, void* d_ws, size_t ws_size,
                              hipStream_t stream) {
    const float* Hp  = (const float*)d_in[0];
    const float* Hq  = (const float*)d_in[1];
    const float* Ha  = (const float*)d_in[2];
    const float* W5  = (const float*)d_in[3];
    const float* W6  = (const float*)d_in[4];
    const float* W7  = (const float*)d_in[5];
    const float* W8  = (const float*)d_in[6];
    const float* b8  = (const float*)d_in[7];
    const float* W9  = (const float*)d_in[8];
    const float* W10 = (const float*)d_in[9];
    const float* W11 = (const float*)d_in[10];
    const float* W12 = (const float*)d_in[11];
    const float* W13 = (const float*)d_in[12];
    const float* W14 = (const float*)d_in[13];
    const float* b14 = (const float*)d_in[14];
    const float* V   = (const float*)d_in[15];
    float* out = (float*)d_out;
    (void)in_sizes; (void)n_in; (void)out_size; (void)ws_size;

    char* base = (char*)d_ws;
    size_t off = 0;
    auto take = [&](size_t bytes) { char* p = base + off; off += (bytes + 15) & ~15UL; return p; };

    __bf16* W5t_h  = (__bf16*)take(1179648);
    __bf16* W5t_l  = (__bf16*)take(1179648);
    __bf16* WsQT_h = (__bf16*)take(2359296);
    __bf16* WsQT_l = (__bf16*)take(2359296);
    __bf16* W6t_h  = (__bf16*)take(3538944);
    __bf16* W6t_l  = (__bf16*)take(3538944);
    __bf16* W1112T = (__bf16*)take(2359296);
    __bf16* W78t   = (__bf16*)take(1179648);
    __bf16* W1314t = (__bf16*)take(2359296);
    float* ra     = (float*)take(12288);
    float* rq     = (float*)take(4096);
    float* amax   = (float*)take(524288);
    int*   topidx = (int*)take(256);
    __bf16* Ha_h  = (__bf16*)take(4718592);
    __bf16* Ha_l  = (__bf16*)take(4718592);
    __bf16* Hq_h  = (__bf16*)take(1572864);
    __bf16* Hq_l  = (__bf16*)take(1572864);
    __bf16* Hps_h = (__bf16*)take(6291456);
    __bf16* Hps_l = (__bf16*)take(6291456);
    __bf16* C1_h  = (__bf16*)take(4718592);
    __bf16* C1_l  = (__bf16*)take(4718592);
    __bf16* HqS_h = (__bf16*)take(3145728);
    __bf16* HqS_l = (__bf16*)take(3145728);
    __bf16* c1_h  = (__bf16*)take(6291456);
    __bf16* c1_l  = (__bf16*)take(6291456);
    __bf16* c4_h  = (__bf16*)take(4718592);
    __bf16* c4_l  = (__bf16*)take(4718592);
    __bf16* Ho_h  = (__bf16*)take(4718592);
    __bf16* Ho_l  = (__bf16*)take(4718592);
    __bf16* hats_h = (__bf16*)take(14155776);
    __bf16* hats_l = (__bf16*)take(14155776);
    __bf16* bar_h  = (__bf16*)take(4718592);
    __bf16* HqS2_bf   = (__bf16*)take(3145728);
    __bf16* HpsW12_bf = (__bf16*)take(6291456);
    __bf16* HoW11_bf  = (__bf16*)take(4718592);
    __bf16* S_h    = (__bf16*)take(884736);
    float* bar  = (float*)take(9437184);
    float* S    = (float*)take(1769472);
    float* gts  = (float*)take(884736);

    dim3 blk(256);

    prep_kernel<<<6336, blk, 0, stream>>>(W5, W6, W7, W8, W9, W10, W11, W12, W13, W14,
                                          W5t_h, W5t_l, WsQT_h, WsQT_l, W6t_h, W6t_l,
                                          W1112T, W78t, W1314t);
    cvt2n_kernel<<<4096, blk, 0, stream>>>(Ha, Ha_h, Ha_l, ra, Hq, Hq_h, Hq_l, rq);

    simmax_kernel<<<1024, blk, 0, stream>>>(Hp, Ha_h, Ha_l, Hq_h, Hq_l, ra, rq, amax);
    score_top2_kernel<<<32, dim3(64), 0, stream>>>(amax, topidx);
    gather_kernel<<<12288, blk, 0, stream>>>(Hp, topidx, Hps_h, Hps_l);

    // batched projection GEMMs (128x128 tiles)
    {
        PXArgs pa{};
        pa.s[0] = { Ha_h, Ha_l, W5t_h, W5t_l, C1_h, C1_l, 768, 24 };
        pa.s[1] = { Hq_h, Hq_l, WsQT_h, WsQT_l, HqS_h, HqS_l, 1536, 8 };
        pa.s[2] = { Hps_h, Hps_l, WsQT_h, WsQT_l, c1_h, c1_l, 768, 32 };
        projxb_kernel<<<432, blk, 0, stream>>>(pa);
    }
    {
        PPArgs pa{};
        pa.s[0] = { Hq_h, W1112T, HqS2_bf, 1536, 8 };
        pa.s[1] = { Hps_h, W1112T + (long)768 * 768, HpsW12_bf, 768, 32 };
        projpb_kernel<<<288, blk, 0, stream>>>(pa);
    }

    // stage-2 fused QK + hats
    {
        QHArgs qa{}; int si = 0;
        for (int i = 0; i < 4; i++) {
            int jj = 0;
            for (int j = 0; j < 4; j++) {
                if (j == i) continue;
                QHSeg& s = qa.s[si];
                s.GLh = C1_h + (long)i * 24 * 768; s.GLl = C1_l + (long)i * 24 * 768;
                s.HYh = Ha_h + (long)j * 24 * 768; s.HYl = Ha_l + (long)j * 24 * 768;
                s.outH = hats_h + (long)i * 24 * 2304 + jj * 768;
                s.outL = hats_l + (long)i * 24 * 2304 + jj * 768;
                s.glB = 73728; s.hyB = 73728; s.oB = 221184;
                si++; jj++;
            }
        }
        qkh_kernel<<<12 * 32, blk, 0, stream>>>(qa);
    }
    // bar = hats@W6 (128x128, K=2304); gate; c4 (128x128); HoW11 (plain 128x128)
    mgemm3b_kernel<1><<<dim3(24, 6), blk, 0, stream>>>(hats_h, hats_l, 2304, W6t_h, W6t_l, bar, 768, bar_h, nullptr);
    mgemm_gate_kernel<<<dim3(48, 12), blk, 0, stream>>>(bar_h, W78t, b8, Ha, bar, Ho_h, Ho_l);
    mgemm3b_kernel<2><<<dim3(24, 6), blk, 0, stream>>>(Ho_h, Ho_l, 768, WsQT_h + (long)768 * 768, WsQT_l + (long)768 * 768, nullptr, 768, c4_h, c4_l);
    mgemmb_kernel<<<dim3(24, 6), blk, 0, stream>>>(Ho_h, 768, W1112T, HoW11_bf, 768);

    // match: fused QK + softmax + colmax S (18 segs)
    {
        QSArgs qa{};
        auto set = [&](int k, const __bf16* GLh, const __bf16* GLl, long glB, int ldGL,
                       const __bf16* HYh, const __bf16* HYl, long hyB, int ldHY,
                       const __bf16* B, long bB, int ldB,
                       float* oF, __bf16* oH, int shape) {
            QSSeg& s = qa.s[k];
            s.GLh = GLh; s.GLl = GLl; s.HYh = HYh; s.HYl = HYl; s.B = B;
            s.outF = oF; s.outH = oH;
            s.glB = glB; s.hyB = hyB; s.bB = bB;
            s.ldGL = ldGL; s.ldHY = ldHY; s.ldB = ldB; s.shape = shape;
        };
        set(0, c1_h, c1_l, 98304, 768, Hq_h, Hq_l, 24576, 768,
            HqS2_bf, 49152, 1536, S, S_h, 1);
        for (int i = 0; i < 4; i++) {
            set(1 + i, c1_h, c1_l, 98304, 768,
                Ho_h + (long)i * 24 * 768, Ho_l + (long)i * 24 * 768, 73728, 768,
                HoW11_bf + (long)i * 24 * 768, 73728, 768,
                S + (long)(1 + i) * 49152, S_h + (long)(1 + i) * 49152, 2);
            set(5 + i, HqS_h, HqS_l, 49152, 1536,
                Ho_h + (long)i * 24 * 768, Ho_l + (long)i * 24 * 768, 73728, 768,
                HoW11_bf + (long)i * 24 * 768, 73728, 768,
                S + (long)(5 + i) * 49152, S_h + (long)(5 + i) * 49152, 3);
            set(9 + i, c4_h + (long)i * 24 * 768, c4_l + (long)i * 24 * 768, 73728, 768,
                Hq_h, Hq_l, 24576, 768,
                HqS2_bf + 768, 49152, 1536,
                S + (long)(5 + i) * 49152 + 768, S_h + (long)(5 + i) * 49152 + 768, 4);
        }
        set(13, HqS_h + 768, HqS_l + 768, 49152, 1536, Hps_h, Hps_l, 98304, 768,
            HpsW12_bf, 98304, 768, S + 768, S_h + 768, 5);
        for (int i = 0; i < 4; i++)
            set(14 + i, c4_h + (long)i * 24 * 768, c4_l + (long)i * 24 * 768, 73728, 768,
                Hps_h, Hps_l, 98304, 768,
                HpsW12_bf, 98304, 768,
                S + (long)(1 + i) * 49152 + 768, S_h + (long)(1 + i) * 49152 + 768, 6);
        qks_kernel<<<18 * 32, blk, 0, stream>>>(qa);
    }

    // gating: gts = [Sxy|Syx] @ [W13;W14] + b14 (64x64, M=288)
    mgemm_kernel<1, 0><<<dim3(5, 12), blk, 0, stream>>>(S_h, 1536, 288, W1314t, b14, gts, 768, nullptr);

    logits_lsm_kernel<<<32, blk, 0, stream>>>(S, gts, V, out);
}

// Round 12
// 440.027 us; speedup vs baseline: 1.1144x; 1.1144x over previous
//
#include <hip/hip_runtime.h>
#include <math.h>

// B=32, N=32, P=64, Q=32, A=24, M=4, L=768, K=2

typedef __bf16 bf16x8 __attribute__((ext_vector_type(8)));
typedef float f32x4 __attribute__((ext_vector_type(4)));

#define MFMA __builtin_amdgcn_mfma_f32_16x16x32_bf16

// ---------------- prep: coalesced LDS-tile transposes ----------------
__global__ __launch_bounds__(256) void prep_kernel(
    const float* __restrict__ W5, const float* __restrict__ W6,
    const float* __restrict__ W7, const float* __restrict__ W8,
    const float* __restrict__ W9, const float* __restrict__ W10,
    const float* __restrict__ W11, const float* __restrict__ W12,
    const float* __restrict__ W13, const float* __restrict__ W14,
    __bf16* __restrict__ W5t_h, __bf16* __restrict__ W5t_l,
    __bf16* __restrict__ WsQT_h, __bf16* __restrict__ WsQT_l,
    __bf16* __restrict__ W6t_h, __bf16* __restrict__ W6t_l,
    __bf16* __restrict__ W1112T, __bf16* __restrict__ W78t,
    __bf16* __restrict__ W1314t) {
    __shared__ float T[32][33];
    int blk = blockIdx.x;
    int job, rel;
    if (blk < 576) { job = 0; rel = blk; }
    else if (blk < 1728) { job = 1; rel = blk - 576; }
    else if (blk < 3456) { job = 2; rel = blk - 1728; }
    else if (blk < 4608) { job = 3; rel = blk - 3456; }
    else if (blk < 5184) { job = 4; rel = blk - 4608; }
    else { job = 5; rel = blk - 5184; }
    int KT = (job == 2) ? 72 : (job == 5) ? 48 : 24;
    int Kdim = KT * 32;
    int ntile = rel / KT, ktile = rel - ntile * KT;
    int k0 = ktile * 32, n0 = ntile * 32;
    int t = threadIdx.x, tx = t & 31, ty = t >> 5;
#pragma unroll
    for (int s = 0; s < 4; s++) {
        int k = k0 + ty + 8 * s;
        int n = n0 + tx;
        float v;
        switch (job) {
            case 0: v = W5[(long)k * 768 + n]; break;
            case 1: v = (n < 768) ? W9[(long)k * 768 + n] : W10[(long)k * 768 + n - 768]; break;
            case 2: v = W6[(long)k * 768 + n]; break;
            case 3: v = (n < 768) ? W11[(long)k * 768 + n] : W12[(long)k * 768 + n - 768]; break;
            case 4: v = W7[(long)k * 768 + n] + W8[(long)k * 768 + n]; break;
            default: v = (k < 768) ? W13[(long)k * 768 + n] : W14[(long)(k - 768) * 768 + n]; break;
        }
        T[ty + 8 * s][tx] = v;
    }
    __syncthreads();
#pragma unroll
    for (int s = 0; s < 4; s++) {
        int n = n0 + ty + 8 * s;
        int k = k0 + tx;
        float v = T[tx][ty + 8 * s];
        long o = (long)n * Kdim + k;
        __bf16 h = (__bf16)v;
        switch (job) {
            case 0: W5t_h[o] = h; W5t_l[o] = (__bf16)(v - (float)h); break;
            case 1: WsQT_h[o] = h; WsQT_l[o] = (__bf16)(v - (float)h); break;
            case 2: W6t_h[o] = h; W6t_l[o] = (__bf16)(v - (float)h); break;
            case 3: W1112T[o] = h; break;
            case 4: W78t[o] = h; break;
            default: W1314t[o] = h; break;
        }
    }
}

// ---------------- cvt2 + rnorm fused (Ha + Hq in one launch) ----------------
__global__ __launch_bounds__(256) void cvt2n_kernel(
    const float* __restrict__ Ha, __bf16* __restrict__ Ha_h, __bf16* __restrict__ Ha_l,
    float* __restrict__ ra,
    const float* __restrict__ Hq, __bf16* __restrict__ Hq_h, __bf16* __restrict__ Hq_l,
    float* __restrict__ rq) {
    long row = blockIdx.x;
    const float* src; __bf16 *h, *l; float* rn;
    if (row < 3072) { src = Ha; h = Ha_h; l = Ha_l; rn = ra; }
    else { row -= 3072; src = Hq; h = Hq_h; l = Hq_l; rn = rq; }
    int t = threadIdx.x;
    const float* sr = src + row * 768;
    float ss = 0.f;
#pragma unroll
    for (int i = 0; i < 3; i++) {
        int idx = t + i * 256;
        float v = sr[idx];
        __bf16 hv = (__bf16)v;
        h[row * 768 + idx] = hv; l[row * 768 + idx] = (__bf16)(v - (float)hv);
        ss += v * v;
    }
    for (int o = 32; o; o >>= 1) ss += __shfl_xor(ss, o);
    __shared__ float red[4];
    if ((t & 63) == 0) red[t >> 6] = ss;
    __syncthreads();
    if (t == 0) rn[row] = 1.f / fmaxf(sqrtf(red[0] + red[1] + red[2] + red[3]), 1e-8f);
}

// ---------------- MFMA bf16x3 simmax with fused Hp row norms (pipelined) ----------------
__global__ __launch_bounds__(256) void simmax_kernel(
    const float* __restrict__ Hp,
    const __bf16* __restrict__ Ha_h, const __bf16* __restrict__ Ha_l,
    const __bf16* __restrict__ Hq_h, const __bf16* __restrict__ Hq_l,
    const float* __restrict__ ra, const float* __restrict__ rq,
    float* __restrict__ amax) {
    constexpr int LDT = 72;
    __shared__ alignas(16) __bf16 Ah[64 * LDT];
    __shared__ alignas(16) __bf16 Al[64 * LDT];
    __shared__ alignas(16) __bf16 Bh[128 * LDT];
    __shared__ alignas(16) __bf16 Bl[128 * LDT];
    __shared__ float rp_lds[64];
    __shared__ float wred[4][128];
    int b = blockIdx.x >> 5, n = blockIdx.x & 31;
    int t = threadIdx.x;
    const float* Ap = Hp + ((long)b * 2048 + n * 64) * 768;
    int srow = t >> 2, kq = (t & 3) << 4;
    int brow = t >> 1, kh = (t & 1) << 5;
    const __bf16 *Bsh, *Bsl;
    if (brow < 96) {
        Bsh = Ha_h + (long)b * 73728 + (long)brow * 768;
        Bsl = Ha_l + (long)b * 73728 + (long)brow * 768;
    } else {
        Bsh = Hq_h + (long)b * 24576 + (long)(brow - 96) * 768;
        Bsl = Hq_l + (long)b * 24576 + (long)(brow - 96) * 768;
    }
    int w = t >> 6, l = t & 63;
    int fr = l & 15, g = l >> 4;
    int wr = w << 4;
    f32x4 acc[8] = {};
    float ss = 0.f;
    const float* Arow = Ap + (long)srow * 768 + kq;
    float4 av0, av1, av2, av3;
    bf16x8 vbh0, vbh1, vbh2, vbh3, vbl0, vbl1, vbl2, vbl3;
    auto LOADS = [&](int k0) {
        av0 = *(const float4*)(Arow + k0 + 0);
        av1 = *(const float4*)(Arow + k0 + 4);
        av2 = *(const float4*)(Arow + k0 + 8);
        av3 = *(const float4*)(Arow + k0 + 12);
        vbh0 = *(const bf16x8*)(Bsh + k0 + kh);
        vbh1 = *(const bf16x8*)(Bsh + k0 + kh + 8);
        vbh2 = *(const bf16x8*)(Bsh + k0 + kh + 16);
        vbh3 = *(const bf16x8*)(Bsh + k0 + kh + 24);
        vbl0 = *(const bf16x8*)(Bsl + k0 + kh);
        vbl1 = *(const bf16x8*)(Bsl + k0 + kh + 8);
        vbl2 = *(const bf16x8*)(Bsl + k0 + kh + 16);
        vbl3 = *(const bf16x8*)(Bsl + k0 + kh + 24);
    };
    LOADS(0);
    for (int k0 = 0; k0 < 768; k0 += 64) {
        float va[16];
        *(float4*)(va + 0) = av0; *(float4*)(va + 4) = av1;
        *(float4*)(va + 8) = av2; *(float4*)(va + 12) = av3;
        bf16x8 h0, h1, l0, l1;
#pragma unroll
        for (int i = 0; i < 8; i++) {
            float v = va[i]; __bf16 hv = (__bf16)v;
            h0[i] = hv; l0[i] = (__bf16)(v - (float)hv); ss += v * v;
            v = va[8 + i]; hv = (__bf16)v;
            h1[i] = hv; l1[i] = (__bf16)(v - (float)hv); ss += v * v;
        }
        bf16x8 sbh0 = vbh0, sbh1 = vbh1, sbh2 = vbh2, sbh3 = vbh3;
        bf16x8 sbl0 = vbl0, sbl1 = vbl1, sbl2 = vbl2, sbl3 = vbl3;
        __syncthreads();
        *(bf16x8*)(&Ah[srow * LDT + kq]) = h0;
        *(bf16x8*)(&Ah[srow * LDT + kq + 8]) = h1;
        *(bf16x8*)(&Al[srow * LDT + kq]) = l0;
        *(bf16x8*)(&Al[srow * LDT + kq + 8]) = l1;
        *(bf16x8*)(&Bh[brow * LDT + kh]) = sbh0;
        *(bf16x8*)(&Bh[brow * LDT + kh + 8]) = sbh1;
        *(bf16x8*)(&Bh[brow * LDT + kh + 16]) = sbh2;
        *(bf16x8*)(&Bh[brow * LDT + kh + 24]) = sbh3;
        *(bf16x8*)(&Bl[brow * LDT + kh]) = sbl0;
        *(bf16x8*)(&Bl[brow * LDT + kh + 8]) = sbl1;
        *(bf16x8*)(&Bl[brow * LDT + kh + 16]) = sbl2;
        *(bf16x8*)(&Bl[brow * LDT + kh + 24]) = sbl3;
        if (k0 + 64 < 768) LOADS(k0 + 64);
        __syncthreads();
#pragma unroll
        for (int sub = 0; sub < 2; sub++) {
            int kb = sub * 32 + g * 8;
            bf16x8 fah = *(const bf16x8*)(&Ah[(wr + fr) * LDT + kb]);
            bf16x8 fal = *(const bf16x8*)(&Al[(wr + fr) * LDT + kb]);
#pragma unroll
            for (int c = 0; c < 8; c++) {
                bf16x8 fbh = *(const bf16x8*)(&Bh[(c * 16 + fr) * LDT + kb]);
                bf16x8 fbl = *(const bf16x8*)(&Bl[(c * 16 + fr) * LDT + kb]);
                acc[c] = MFMA(fah, fbh, acc[c], 0, 0, 0);
                acc[c] = MFMA(fah, fbl, acc[c], 0, 0, 0);
                acc[c] = MFMA(fal, fbh, acc[c], 0, 0, 0);
            }
        }
    }
    ss += __shfl_xor(ss, 1);
    ss += __shfl_xor(ss, 2);
    if ((t & 3) == 0) rp_lds[srow] = 1.f / fmaxf(sqrtf(ss), 1e-8f);
    __syncthreads();
    float rpv[4];
#pragma unroll
    for (int r = 0; r < 4; r++) rpv[r] = rp_lds[wr + g * 4 + r];
#pragma unroll
    for (int c = 0; c < 8; c++) {
        float mx = acc[c][0] * rpv[0];
        mx = fmaxf(mx, acc[c][1] * rpv[1]);
        mx = fmaxf(mx, acc[c][2] * rpv[2]);
        mx = fmaxf(mx, acc[c][3] * rpv[3]);
        mx = fmaxf(mx, __shfl_xor(mx, 16));
        mx = fmaxf(mx, __shfl_xor(mx, 32));
        if (g == 0) wred[w][c * 16 + fr] = mx;
    }
    __syncthreads();
    if (t < 128) {
        float m = fmaxf(fmaxf(wred[0][t], wred[1][t]), fmaxf(wred[2][t], wred[3][t]));
        float rc = (t < 96) ? ra[b * 96 + t] : rq[b * 32 + (t - 96)];
        amax[((long)b * 32 + n) * 128 + t] = m * rc;
    }
}

__global__ void score_top2_kernel(const float* __restrict__ amax, int* __restrict__ idx) {
    int b = blockIdx.x, t = threadIdx.x;
    __shared__ float sc[32];
    if (t < 32) {
        const float* am = amax + ((long)b * 32 + t) * 128;
        float sa = 0.f, sq = 0.f;
        for (int c = 0; c < 96; c++) sa += am[c];
        for (int c = 96; c < 128; c++) sq += am[c];
        sc[t] = sa / 24.f + sq / 32.f;
    }
    __syncthreads();
    if (t == 0) {
        float m0 = -1e30f; int i0 = 0;
        for (int n = 0; n < 32; n++) if (sc[n] > m0) { m0 = sc[n]; i0 = n; }
        float m1 = -1e30f; int i1 = 0;
        for (int n = 0; n < 32; n++) if (n != i0 && sc[n] > m1) { m1 = sc[n]; i1 = n; }
        idx[b * 2] = i0; idx[b * 2 + 1] = i1;
    }
}

__global__ void gather_kernel(const float* __restrict__ Hp, const int* __restrict__ idx,
                              __bf16* __restrict__ Hps_h, __bf16* __restrict__ Hps_l) {
    long i = (long)blockIdx.x * 256 + threadIdx.x;
    if (i >= (long)32 * 128 * 768) return;
    int l = (int)(i % 768);
    long r = i / 768;
    int x = (int)(r % 128); int b = (int)(r / 128);
    int k = x >> 6, p = x & 63;
    int n = idx[b * 2 + k];
    float v = Hp[((long)b * 2048 + n * 64 + p) * 768 + l];
    __bf16 h = (__bf16)v; Hps_h[i] = h; Hps_l[i] = (__bf16)(v - (float)h);
}

// ---------------- bf16 MFMA GEMM 64x64 (plain, pipelined) ----------------
template <int BIASF, int BOUT>
__global__ __launch_bounds__(256) void mgemm_kernel(
    const __bf16* __restrict__ A, int Kdim, int Mtot,
    const __bf16* __restrict__ Wt, const float* __restrict__ bias,
    float* __restrict__ C, int ldc, __bf16* __restrict__ Cb) {
    constexpr int LDT = 80;
    __shared__ alignas(16) __bf16 As[64 * LDT];
    __shared__ alignas(16) __bf16 Bs[64 * LDT];
    int t = threadIdx.x;
    int rowBase = blockIdx.x << 6, colBase = blockIdx.y << 6;
    int srow = t >> 2, skof = (t & 3) << 3;
    int arow = rowBase + srow;
    bool aok = arow < Mtot;
    const __bf16* Ap = A + (long)(aok ? arow : rowBase) * Kdim + skof;
    const __bf16* Wp = Wt + (long)(colBase + srow) * Kdim + skof;
    int w = t >> 6, l = t & 63;
    int wr = (w >> 1) << 5, wc = (w & 1) << 5;
    int fr = l & 15, g = l >> 4;
    f32x4 acc[2][2] = {};
    int nk = Kdim >> 6;
    bf16x8 a0, a1, w0, w1;
    auto LOADM = [&]() {
        a0 = *(const bf16x8*)(Ap); a1 = *(const bf16x8*)(Ap + 32);
        w0 = *(const bf16x8*)(Wp); w1 = *(const bf16x8*)(Wp + 32);
        Ap += 64; Wp += 64;
    };
    LOADM();
    for (int ks = 0; ks < nk; ks++) {
        __syncthreads();
        *(bf16x8*)(&As[srow * LDT + skof]) = a0;
        *(bf16x8*)(&As[srow * LDT + 32 + skof]) = a1;
        *(bf16x8*)(&Bs[srow * LDT + skof]) = w0;
        *(bf16x8*)(&Bs[srow * LDT + 32 + skof]) = w1;
        if (ks + 1 < nk) LOADM();
        __syncthreads();
#pragma unroll
        for (int sub = 0; sub < 2; sub++) {
            int ko = sub * 32 + g * 8;
            bf16x8 fa0 = *(const bf16x8*)(&As[(wr + fr) * LDT + ko]);
            bf16x8 fa1 = *(const bf16x8*)(&As[(wr + 16 + fr) * LDT + ko]);
            bf16x8 fb0 = *(const bf16x8*)(&Bs[(wc + fr) * LDT + ko]);
            bf16x8 fb1 = *(const bf16x8*)(&Bs[(wc + 16 + fr) * LDT + ko]);
            acc[0][0] = MFMA(fa0, fb0, acc[0][0], 0, 0, 0);
            acc[0][1] = MFMA(fa0, fb1, acc[0][1], 0, 0, 0);
            acc[1][0] = MFMA(fa1, fb0, acc[1][0], 0, 0, 0);
            acc[1][1] = MFMA(fa1, fb1, acc[1][1], 0, 0, 0);
        }
    }
#pragma unroll
    for (int fi = 0; fi < 2; fi++)
#pragma unroll
    for (int fj = 0; fj < 2; fj++)
#pragma unroll
    for (int r = 0; r < 4; r++) {
        int row = rowBase + wr + fi * 16 + g * 4 + r;
        int col = colBase + wc + fj * 16 + (l & 15);
        if (row < Mtot) {
            float v = acc[fi][fj][r];
            if (BIASF) v += bias[col];
            if (BOUT == 0) C[(long)row * ldc + col] = v;
            else Cb[(long)row * ldc + col] = (__bf16)v;
        }
    }
}

// ---------------- mgemm + fused sigmoid-gate epilogue ----------------
__global__ __launch_bounds__(256) void mgemm_gate_kernel(
    const __bf16* __restrict__ A, const __bf16* __restrict__ Wt, const float* __restrict__ bias,
    const float* __restrict__ HaF, const float* __restrict__ barF,
    __bf16* __restrict__ Ho_h, __bf16* __restrict__ Ho_l) {
    constexpr int LDT = 80;
    constexpr int Kdim = 768;
    __shared__ alignas(16) __bf16 As[64 * LDT];
    __shared__ alignas(16) __bf16 Bs[64 * LDT];
    int t = threadIdx.x;
    int rowBase = blockIdx.x << 6, colBase = blockIdx.y << 6;
    int srow = t >> 2, skof = (t & 3) << 3;
    const __bf16* Ap = A + (long)(rowBase + srow) * Kdim + skof;
    const __bf16* Wp = Wt + (long)(colBase + srow) * Kdim + skof;
    int w = t >> 6, l = t & 63;
    int wr = (w >> 1) << 5, wc = (w & 1) << 5;
    int fr = l & 15, g = l >> 4;
    f32x4 acc[2][2] = {};
    bf16x8 a0, a1, w0, w1;
    auto LOADM = [&]() {
        a0 = *(const bf16x8*)(Ap); a1 = *(const bf16x8*)(Ap + 32);
        w0 = *(const bf16x8*)(Wp); w1 = *(const bf16x8*)(Wp + 32);
        Ap += 64; Wp += 64;
    };
    LOADM();
    for (int ks = 0; ks < 12; ks++) {
        __syncthreads();
        *(bf16x8*)(&As[srow * LDT + skof]) = a0;
        *(bf16x8*)(&As[srow * LDT + 32 + skof]) = a1;
        *(bf16x8*)(&Bs[srow * LDT + skof]) = w0;
        *(bf16x8*)(&Bs[srow * LDT + 32 + skof]) = w1;
        if (ks + 1 < 12) LOADM();
        __syncthreads();
#pragma unroll
        for (int sub = 0; sub < 2; sub++) {
            int ko = sub * 32 + g * 8;
            bf16x8 fa0 = *(const bf16x8*)(&As[(wr + fr) * LDT + ko]);
            bf16x8 fa1 = *(const bf16x8*)(&As[(wr + 16 + fr) * LDT + ko]);
            bf16x8 fb0 = *(const bf16x8*)(&Bs[(wc + fr) * LDT + ko]);
            bf16x8 fb1 = *(const bf16x8*)(&Bs[(wc + 16 + fr) * LDT + ko]);
            acc[0][0] = MFMA(fa0, fb0, acc[0][0], 0, 0, 0);
            acc[0][1] = MFMA(fa0, fb1, acc[0][1], 0, 0, 0);
            acc[1][0] = MFMA(fa1, fb0, acc[1][0], 0, 0, 0);
            acc[1][1] = MFMA(fa1, fb1, acc[1][1], 0, 0, 0);
        }
    }
#pragma unroll
    for (int fi = 0; fi < 2; fi++)
#pragma unroll
    for (int fj = 0; fj < 2; fj++)
#pragma unroll
    for (int r = 0; r < 4; r++) {
        int row = rowBase + wr + fi * 16 + g * 4 + r;
        int col = colBase + wc + fj * 16 + (l & 15);
        float v = acc[fi][fj][r] + bias[col];
        float gt = 1.f / (1.f + expf(-v));
        long o = (long)row * 768 + col;
        float hv = gt * HaF[o] + (1.f - gt) * barF[o];
        __bf16 hb = (__bf16)hv;
        Ho_h[o] = hb; Ho_l[o] = (__bf16)(hv - (float)hb);
    }
}

// ---------------- bf16x3 split-precision MFMA GEMM 64x64 (pipelined) ----------------
template <int OUT>
__global__ __launch_bounds__(256) void mgemm3_kernel(
    const __bf16* __restrict__ Ah, const __bf16* __restrict__ Al, int Kdim, int Mtot,
    const __bf16* __restrict__ Wh, const __bf16* __restrict__ Wl,
    float* __restrict__ C, int ldc, __bf16* __restrict__ Ch, __bf16* __restrict__ Cl) {
    constexpr int LDT = 80;
    __shared__ alignas(16) __bf16 Ahs[64 * LDT];
    __shared__ alignas(16) __bf16 Als[64 * LDT];
    __shared__ alignas(16) __bf16 Bhs[64 * LDT];
    __shared__ alignas(16) __bf16 Bls[64 * LDT];
    int t = threadIdx.x;
    int rowBase = blockIdx.x << 6, colBase = blockIdx.y << 6;
    int srow = t >> 2, skof = (t & 3) << 3;
    int arow = rowBase + srow;
    bool aok = arow < Mtot;
    long aoff = (long)(aok ? arow : rowBase) * Kdim + skof;
    long woff = (long)(colBase + srow) * Kdim + skof;
    const __bf16* Aph = Ah + aoff;
    const __bf16* Apl = Al + aoff;
    const __bf16* Wph = Wh + woff;
    const __bf16* Wpl = Wl + woff;
    int w = t >> 6, l = t & 63;
    int wr = (w >> 1) << 5, wc = (w & 1) << 5;
    int fr = l & 15, g = l >> 4;
    f32x4 acc[2][2] = {};
    int nk = Kdim >> 6;
    bf16x8 ah0, ah1, al0, al1, wh0, wh1, wl0, wl1;
    auto LOADM = [&]() {
        ah0 = *(const bf16x8*)(Aph); ah1 = *(const bf16x8*)(Aph + 32);
        al0 = *(const bf16x8*)(Apl); al1 = *(const bf16x8*)(Apl + 32);
        wh0 = *(const bf16x8*)(Wph); wh1 = *(const bf16x8*)(Wph + 32);
        wl0 = *(const bf16x8*)(Wpl); wl1 = *(const bf16x8*)(Wpl + 32);
        Aph += 64; Apl += 64; Wph += 64; Wpl += 64;
    };
    LOADM();
    for (int ks = 0; ks < nk; ks++) {
        __syncthreads();
        *(bf16x8*)(&Ahs[srow * LDT + skof]) = ah0; *(bf16x8*)(&Ahs[srow * LDT + 32 + skof]) = ah1;
        *(bf16x8*)(&Als[srow * LDT + skof]) = al0; *(bf16x8*)(&Als[srow * LDT + 32 + skof]) = al1;
        *(bf16x8*)(&Bhs[srow * LDT + skof]) = wh0; *(bf16x8*)(&Bhs[srow * LDT + 32 + skof]) = wh1;
        *(bf16x8*)(&Bls[srow * LDT + skof]) = wl0; *(bf16x8*)(&Bls[srow * LDT + 32 + skof]) = wl1;
        if (ks + 1 < nk) LOADM();
        __syncthreads();
#pragma unroll
        for (int sub = 0; sub < 2; sub++) {
            int ko = sub * 32 + g * 8;
            bf16x8 fah[2], fal[2], fbh[2], fbl[2];
            fah[0] = *(const bf16x8*)(&Ahs[(wr + fr) * LDT + ko]);
            fah[1] = *(const bf16x8*)(&Ahs[(wr + 16 + fr) * LDT + ko]);
            fal[0] = *(const bf16x8*)(&Als[(wr + fr) * LDT + ko]);
            fal[1] = *(const bf16x8*)(&Als[(wr + 16 + fr) * LDT + ko]);
            fbh[0] = *(const bf16x8*)(&Bhs[(wc + fr) * LDT + ko]);
            fbh[1] = *(const bf16x8*)(&Bhs[(wc + 16 + fr) * LDT + ko]);
            fbl[0] = *(const bf16x8*)(&Bls[(wc + fr) * LDT + ko]);
            fbl[1] = *(const bf16x8*)(&Bls[(wc + 16 + fr) * LDT + ko]);
#pragma unroll
            for (int i = 0; i < 2; i++)
#pragma unroll
            for (int j = 0; j < 2; j++) {
                acc[i][j] = MFMA(fah[i], fbh[j], acc[i][j], 0, 0, 0);
                acc[i][j] = MFMA(fah[i], fbl[j], acc[i][j], 0, 0, 0);
                acc[i][j] = MFMA(fal[i], fbh[j], acc[i][j], 0, 0, 0);
            }
        }
    }
#pragma unroll
    for (int fi = 0; fi < 2; fi++)
#pragma unroll
    for (int fj = 0; fj < 2; fj++)
#pragma unroll
    for (int r = 0; r < 4; r++) {
        int row = rowBase + wr + fi * 16 + g * 4 + r;
        int col = colBase + wc + fj * 16 + (l & 15);
        if (row < Mtot) {
            float v = acc[fi][fj][r];
            long o = (long)row * ldc + col;
            if (OUT == 0) { C[o] = v; }
            else if (OUT == 1) { C[o] = v; Ch[o] = (__bf16)v; }
            else {
                __bf16 h = (__bf16)v;
                Ch[o] = h; Cl[o] = (__bf16)(v - (float)h);
            }
        }
    }
}

// ---------------- batched projection GEMMs (one launch each type) ----------------
struct PXSeg { const __bf16 *Ah, *Al, *Wh, *Wl; __bf16 *Ch, *Cl; int Mtot, ldc, gx; };
struct PXArgs { PXSeg s[3]; };

__global__ __launch_bounds__(256) void projx_kernel(PXArgs args) {
    constexpr int LDT = 80;
    __shared__ alignas(16) __bf16 Ahs[64 * LDT];
    __shared__ alignas(16) __bf16 Als[64 * LDT];
    __shared__ alignas(16) __bf16 Bhs[64 * LDT];
    __shared__ alignas(16) __bf16 Bls[64 * LDT];
    int bid = blockIdx.x;
    int seg = (bid < 576) ? 0 : (bid < 960) ? 1 : 2;
    int rel = bid - ((seg == 0) ? 0 : (seg == 1) ? 576 : 960);
    PXSeg sg = args.s[seg];
    int rowBase = (rel % sg.gx) << 6, colBase = (rel / sg.gx) << 6;
    int t = threadIdx.x;
    int srow = t >> 2, skof = (t & 3) << 3;
    long aoff = (long)(rowBase + srow) * 768 + skof;
    long woff = (long)(colBase + srow) * 768 + skof;
    const __bf16* Aph = sg.Ah + aoff;
    const __bf16* Apl = sg.Al + aoff;
    const __bf16* Wph = sg.Wh + woff;
    const __bf16* Wpl = sg.Wl + woff;
    int w = t >> 6, l = t & 63;
    int wr = (w >> 1) << 5, wc = (w & 1) << 5;
    int fr = l & 15, g = l >> 4;
    f32x4 acc[2][2] = {};
    bf16x8 ah0, ah1, al0, al1, wh0, wh1, wl0, wl1;
    auto LOADM = [&]() {
        ah0 = *(const bf16x8*)(Aph); ah1 = *(const bf16x8*)(Aph + 32);
        al0 = *(const bf16x8*)(Apl); al1 = *(const bf16x8*)(Apl + 32);
        wh0 = *(const bf16x8*)(Wph); wh1 = *(const bf16x8*)(Wph + 32);
        wl0 = *(const bf16x8*)(Wpl); wl1 = *(const bf16x8*)(Wpl + 32);
        Aph += 64; Apl += 64; Wph += 64; Wpl += 64;
    };
    LOADM();
    for (int ks = 0; ks < 12; ks++) {
        __syncthreads();
        *(bf16x8*)(&Ahs[srow * LDT + skof]) = ah0; *(bf16x8*)(&Ahs[srow * LDT + 32 + skof]) = ah1;
        *(bf16x8*)(&Als[srow * LDT + skof]) = al0; *(bf16x8*)(&Als[srow * LDT + 32 + skof]) = al1;
        *(bf16x8*)(&Bhs[srow * LDT + skof]) = wh0; *(bf16x8*)(&Bhs[srow * LDT + 32 + skof]) = wh1;
        *(bf16x8*)(&Bls[srow * LDT + skof]) = wl0; *(bf16x8*)(&Bls[srow * LDT + 32 + skof]) = wl1;
        if (ks + 1 < 12) LOADM();
        __syncthreads();
#pragma unroll
        for (int sub = 0; sub < 2; sub++) {
            int ko = sub * 32 + g * 8;
            bf16x8 fah[2], fal[2], fbh[2], fbl[2];
            fah[0] = *(const bf16x8*)(&Ahs[(wr + fr) * LDT + ko]);
            fah[1] = *(const bf16x8*)(&Ahs[(wr + 16 + fr) * LDT + ko]);
            fal[0] = *(const bf16x8*)(&Als[(wr + fr) * LDT + ko]);
            fal[1] = *(const bf16x8*)(&Als[(wr + 16 + fr) * LDT + ko]);
            fbh[0] = *(const bf16x8*)(&Bhs[(wc + fr) * LDT + ko]);
            fbh[1] = *(const bf16x8*)(&Bhs[(wc + 16 + fr) * LDT + ko]);
            fbl[0] = *(const bf16x8*)(&Bls[(wc + fr) * LDT + ko]);
            fbl[1] = *(const bf16x8*)(&Bls[(wc + 16 + fr) * LDT + ko]);
#pragma unroll
            for (int i = 0; i < 2; i++)
#pragma unroll
            for (int j = 0; j < 2; j++) {
                acc[i][j] = MFMA(fah[i], fbh[j], acc[i][j], 0, 0, 0);
                acc[i][j] = MFMA(fah[i], fbl[j], acc[i][j], 0, 0, 0);
                acc[i][j] = MFMA(fal[i], fbh[j], acc[i][j], 0, 0, 0);
            }
        }
    }
#pragma unroll
    for (int fi = 0; fi < 2; fi++)
#pragma unroll
    for (int fj = 0; fj < 2; fj++)
#pragma unroll
    for (int r = 0; r < 4; r++) {
        int row = rowBase + wr + fi * 16 + g * 4 + r;
        int col = colBase + wc + fj * 16 + (l & 15);
        if (row < sg.Mtot) {
            float v = acc[fi][fj][r];
            long o = (long)row * sg.ldc + col;
            __bf16 h = (__bf16)v;
            sg.Ch[o] = h; sg.Cl[o] = (__bf16)(v - (float)h);
        }
    }
}

struct PPSeg { const __bf16 *A, *Wt; __bf16* Cb; int Mtot, ldc, gx; };
struct PPArgs { PPSeg s[2]; };

__global__ __launch_bounds__(256) void projp_kernel(PPArgs args) {
    constexpr int LDT = 80;
    __shared__ alignas(16) __bf16 As[64 * LDT];
    __shared__ alignas(16) __bf16 Bs[64 * LDT];
    int bid = blockIdx.x;
    int seg = (bid < 384) ? 0 : 1;
    int rel = bid - ((seg == 0) ? 0 : 384);
    PPSeg sg = args.s[seg];
    int rowBase = (rel % sg.gx) << 6, colBase = (rel / sg.gx) << 6;
    int t = threadIdx.x;
    int srow = t >> 2, skof = (t & 3) << 3;
    const __bf16* Ap = sg.A + (long)(rowBase + srow) * 768 + skof;
    const __bf16* Wp = sg.Wt + (long)(colBase + srow) * 768 + skof;
    int w = t >> 6, l = t & 63;
    int wr = (w >> 1) << 5, wc = (w & 1) << 5;
    int fr = l & 15, g = l >> 4;
    f32x4 acc[2][2] = {};
    bf16x8 a0, a1, w0, w1;
    auto LOADM = [&]() {
        a0 = *(const bf16x8*)(Ap); a1 = *(const bf16x8*)(Ap + 32);
        w0 = *(const bf16x8*)(Wp); w1 = *(const bf16x8*)(Wp + 32);
        Ap += 64; Wp += 64;
    };
    LOADM();
    for (int ks = 0; ks < 12; ks++) {
        __syncthreads();
        *(bf16x8*)(&As[srow * LDT + skof]) = a0;
        *(bf16x8*)(&As[srow * LDT + 32 + skof]) = a1;
        *(bf16x8*)(&Bs[srow * LDT + skof]) = w0;
        *(bf16x8*)(&Bs[srow * LDT + 32 + skof]) = w1;
        if (ks + 1 < 12) LOADM();
        __syncthreads();
#pragma unroll
        for (int sub = 0; sub < 2; sub++) {
            int ko = sub * 32 + g * 8;
            bf16x8 fa0 = *(const bf16x8*)(&As[(wr + fr) * LDT + ko]);
            bf16x8 fa1 = *(const bf16x8*)(&As[(wr + 16 + fr) * LDT + ko]);
            bf16x8 fb0 = *(const bf16x8*)(&Bs[(wc + fr) * LDT + ko]);
            bf16x8 fb1 = *(const bf16x8*)(&Bs[(wc + 16 + fr) * LDT + ko]);
            acc[0][0] = MFMA(fa0, fb0, acc[0][0], 0, 0, 0);
            acc[0][1] = MFMA(fa0, fb1, acc[0][1], 0, 0, 0);
            acc[1][0] = MFMA(fa1, fb0, acc[1][0], 0, 0, 0);
            acc[1][1] = MFMA(fa1, fb1, acc[1][1], 0, 0, 0);
        }
    }
#pragma unroll
    for (int fi = 0; fi < 2; fi++)
#pragma unroll
    for (int fj = 0; fj < 2; fj++)
#pragma unroll
    for (int r = 0; r < 4; r++) {
        int row = rowBase + wr + fi * 16 + g * 4 + r;
        int col = colBase + wc + fj * 16 + (l & 15);
        if (row < sg.Mtot)
            sg.Cb[(long)row * sg.ldc + col] = (__bf16)acc[fi][fj][r];
    }
}

// ---------------- fused QK+softmax+hats (stage 2, X=Y=24) ----------------
struct QHSeg {
    const __bf16 *GLh, *GLl, *HYh, *HYl;
    __bf16 *outH, *outL;
    long glB, hyB, oB;
};
struct QHArgs { QHSeg s[12]; };

__global__ __launch_bounds__(256) void qkh_kernel(QHArgs args) {
    constexpr int X = 24, Y = 24, XR = 32, YR = 32, LDT = 72;
    constexpr int YRp = YR + 1;
    constexpr int Ck = 32, Cpad = 40;
    constexpr int scPad = (XR * YRp * 4 + 15) & ~15;
    constexpr int btSz = 2 * 64 * Cpad * 2;
    constexpr int gOff = btSz;
    __shared__ alignas(16) char POOL[18432];
    __bf16* Ah_ = (__bf16*)POOL;
    __bf16* Al_ = Ah_ + XR * LDT;
    int seg = blockIdx.x >> 5, b = blockIdx.x & 31;
    QHSeg sg = args.s[seg];
    int t = threadIdx.x;
    __bf16* Bh_ = Ah_ + 2 * XR * LDT;
    __bf16* Bl_ = Bh_ + YR * LDT;
    float* sc   = (float*)POOL;
    float* invr = (float*)(POOL + scPad);
    __bf16* Bth = (__bf16*)POOL;
    __bf16* Btl = Bth + 64 * Cpad;
    __bf16* Gh  = (__bf16*)(POOL + gOff);
    __bf16* Gl  = Gh + XR * Cpad;
    int w = t >> 6, l = t & 63, fr = l & 15, g = l >> 4;
    const __bf16* GLbh = sg.GLh + (long)b * sg.glB;
    const __bf16* GLbl = sg.GLl + (long)b * sg.glB;
    const __bf16* HYbh = sg.HYh + (long)b * sg.hyB;
    const __bf16* HYbl = sg.HYl + (long)b * sg.hyB;
    f32x4 acc;
#pragma unroll
    for (int r = 0; r < 4; r++) acc[r] = 0.f;
    for (int k0 = 0; k0 < 768; k0 += 64) {
        __syncthreads();
        for (int v = t; v < (XR + YR) * 16; v += 256) {
            int row = v >> 4, sub = v & 15, hl = sub >> 3, k8 = (sub & 7) << 3;
            bf16x8 val = {};
            __bf16* dst;
            if (row < XR) {
                if (row < X)
                    val = *(const bf16x8*)((hl ? GLbl : GLbh) + (long)row * 768 + k0 + k8);
                dst = (hl ? Al_ : Ah_) + row * LDT + k8;
            } else {
                int r2 = row - XR;
                if (r2 < Y)
                    val = *(const bf16x8*)((hl ? HYbl : HYbh) + (long)r2 * 768 + k0 + k8);
                dst = (hl ? Bl_ : Bh_) + r2 * LDT + k8;
            }
            *(bf16x8*)dst = val;
        }
        __syncthreads();
#pragma unroll
        for (int sub = 0; sub < 2; sub++) {
            int kb = sub * 32 + g * 8;
            int xm = w >> 1, yc = w & 1;
            bf16x8 fah = *(const bf16x8*)(&Ah_[(xm * 16 + fr) * LDT + kb]);
            bf16x8 fal = *(const bf16x8*)(&Al_[(xm * 16 + fr) * LDT + kb]);
            bf16x8 fbh = *(const bf16x8*)(&Bh_[(yc * 16 + fr) * LDT + kb]);
            bf16x8 fbl = *(const bf16x8*)(&Bl_[(yc * 16 + fr) * LDT + kb]);
            acc = MFMA(fah, fbh, acc, 0, 0, 0);
            acc = MFMA(fah, fbl, acc, 0, 0, 0);
            acc = MFMA(fal, fbh, acc, 0, 0, 0);
        }
    }
    __syncthreads();
    {
        int xm = w >> 1, yc = w & 1;
#pragma unroll
        for (int r = 0; r < 4; r++)
            sc[(xm * 16 + g * 4 + r) * YRp + yc * 16 + fr] = acc[r];
    }
    __syncthreads();
    {
        constexpr int TPR = 256 / XR;
        int row = t / TPR, sub = t & (TPR - 1);
        if (row < X) {
            float* sr = sc + row * YRp;
            float m = -1e30f;
            for (int c = sub; c < Y; c += TPR) m = fmaxf(m, sr[c]);
#pragma unroll
            for (int o = 1; o < TPR; o <<= 1) m = fmaxf(m, __shfl_xor(m, o));
            float s = 0.f;
            for (int c = sub; c < Y; c += TPR) { float e = expf(sr[c] - m); sr[c] = e; s += e; }
#pragma unroll
            for (int o = 1; o < TPR; o <<= 1) s += __shfl_xor(s, o);
            if (sub == 0) invr[row] = 1.f / s;
        }
    }
    __syncthreads();
    for (int idx = t; idx < XR * Ck; idx += 256) {
        int r = idx >> 5, c = idx & 31;
        float v = (r < X && c < Y) ? sc[r * YRp + c] * invr[r] : 0.f;
        __bf16 h = (__bf16)v;
        Gh[r * Cpad + c] = h; Gl[r * Cpad + c] = (__bf16)(v - (float)h);
    }
    int bl = t & 63, bc0 = t >> 6;
    for (int n0 = 0; n0 < 768; n0 += 64) {
        __syncthreads();
        for (int c = bc0; c < Ck; c += 4) {
            __bf16 hv = (__bf16)0.f, lv = (__bf16)0.f;
            if (c < Y) { hv = HYbh[(long)c * 768 + n0 + bl]; lv = HYbl[(long)c * 768 + n0 + bl]; }
            Bth[bl * Cpad + c] = hv; Btl[bl * Cpad + c] = lv;
        }
        __syncthreads();
        bf16x8 bh = *(const bf16x8*)(&Bth[(w * 16 + fr) * Cpad + g * 8]);
        bf16x8 blv = *(const bf16x8*)(&Btl[(w * 16 + fr) * Cpad + g * 8]);
        f32x4 a2[2] = {};
#pragma unroll
        for (int m = 0; m < 2; m++) {
            bf16x8 gah = *(const bf16x8*)(&Gh[(m * 16 + fr) * Cpad + g * 8]);
            bf16x8 gal = *(const bf16x8*)(&Gl[(m * 16 + fr) * Cpad + g * 8]);
            a2[m] = MFMA(gah, bh, a2[m], 0, 0, 0);
            a2[m] = MFMA(gal, bh, a2[m], 0, 0, 0);
            a2[m] = MFMA(gah, blv, a2[m], 0, 0, 0);
        }
#pragma unroll
        for (int m = 0; m < 2; m++)
#pragma unroll
        for (int r = 0; r < 4; r++) {
            int row = m * 16 + g * 4 + r;
            if (row < X) {
                float v = fmaxf(a2[m][r], 0.f);
                __bf16 h = (__bf16)v;
                long o = (long)b * sg.oB + (long)row * 2304 + n0 + w * 16 + fr;
                sg.outH[o] = h; sg.outL[o] = (__bf16)(v - (float)h);
            }
        }
    }
}

// ---------------- fused QK+softmax+colmax S (match stage) ----------------
struct QSSeg {
    const __bf16 *GLh, *GLl, *HYh, *HYl, *B;
    float* outF; __bf16* outH;
    long glB, hyB, bB;
    int ldGL, ldHY, ldB, shape;
};
struct QSArgs { QSSeg s[18]; };

template <int X, int Y>
__device__ __forceinline__ void qks_impl(char* POOL, const QSSeg& sg, int b, int t) {
    constexpr int XR = (X + 15) & ~15;
    constexpr int YR = (Y + 15) & ~15;
    constexpr int LDT = 72;
    constexpr int YC = YR / 16;
    constexpr int F = (XR / 16) * YC;
    constexpr int F4 = F / 4;
    constexpr int YRp = YR + 1;
    constexpr int Rk = XR;
    constexpr int Ck = (Y + 31) & ~31;
    constexpr int Cpad = Ck + 8;
    constexpr int NM = Rk / 16;
    constexpr int scPad = (XR * YRp * 4 + 15) & ~15;
    constexpr int invrEnd = scPad + 512;
    constexpr int btSz = 64 * Cpad * 2;
    constexpr int gOff = ((invrEnd > btSz ? invrEnd : btSz) + 15) & ~15;
    static_assert(gOff + 2 * Rk * Cpad * 2 <= 46080, "pool overflow");
    __bf16* Ah_ = (__bf16*)POOL;
    __bf16* Al_ = Ah_ + XR * LDT;
    __bf16* Bh_ = Ah_ + 2 * XR * LDT;
    __bf16* Bl_ = Bh_ + YR * LDT;
    float* sc   = (float*)POOL;
    float* invr = (float*)(POOL + scPad);
    __bf16* Bt  = (__bf16*)POOL;
    __bf16* Gh  = (__bf16*)(POOL + gOff);
    __bf16* Gl  = Gh + Rk * Cpad;
    int w = t >> 6, l = t & 63, fr = l & 15, g = l >> 4;
    const __bf16* GLbh = sg.GLh + (long)b * sg.glB;
    const __bf16* GLbl = sg.GLl + (long)b * sg.glB;
    const __bf16* HYbh = sg.HYh + (long)b * sg.hyB;
    const __bf16* HYbl = sg.HYl + (long)b * sg.hyB;
    f32x4 acc[F4] = {};
    for (int k0 = 0; k0 < 768; k0 += 64) {
        __syncthreads();
        for (int v = t; v < (XR + YR) * 16; v += 256) {
            int row = v >> 4, sub = v & 15, hl = sub >> 3, k8 = (sub & 7) << 3;
            bf16x8 val = {};
            __bf16* dst;
            if (row < XR) {
                if (row < X)
                    val = *(const bf16x8*)((hl ? GLbl : GLbh) + (long)row * sg.ldGL + k0 + k8);
                dst = (hl ? Al_ : Ah_) + row * LDT + k8;
            } else {
                int r2 = row - XR;
                if (r2 < Y)
                    val = *(const bf16x8*)((hl ? HYbl : HYbh) + (long)r2 * sg.ldHY + k0 + k8);
                dst = (hl ? Bl_ : Bh_) + r2 * LDT + k8;
            }
            *(bf16x8*)dst = val;
        }
        __syncthreads();
#pragma unroll
        for (int sub = 0; sub < 2; sub++) {
            int kb = sub * 32 + g * 8;
#pragma unroll
            for (int ff = 0; ff < F4; ff++) {
                int fidx = w + ff * 4;
                int xm = fidx / YC, yc = fidx % YC;
                bf16x8 fah = *(const bf16x8*)(&Ah_[(xm * 16 + fr) * LDT + kb]);
                bf16x8 fal = *(const bf16x8*)(&Al_[(xm * 16 + fr) * LDT + kb]);
                bf16x8 fbh = *(const bf16x8*)(&Bh_[(yc * 16 + fr) * LDT + kb]);
                bf16x8 fbl = *(const bf16x8*)(&Bl_[(yc * 16 + fr) * LDT + kb]);
                acc[ff] = MFMA(fah, fbh, acc[ff], 0, 0, 0);
                acc[ff] = MFMA(fah, fbl, acc[ff], 0, 0, 0);
                acc[ff] = MFMA(fal, fbh, acc[ff], 0, 0, 0);
            }
        }
    }
    __syncthreads();
#pragma unroll
    for (int ff = 0; ff < F4; ff++) {
        int fidx = w + ff * 4;
        int xm = fidx / YC, yc = fidx % YC;
#pragma unroll
        for (int r = 0; r < 4; r++)
            sc[(xm * 16 + g * 4 + r) * YRp + yc * 16 + fr] = acc[ff][r];
    }
    __syncthreads();
    {
        constexpr int TPR = 256 / XR;
        int row = t / TPR, sub = t & (TPR - 1);
        if (row < X) {
            float* sr = sc + row * YRp;
            float m = -1e30f;
            for (int c = sub; c < Y; c += TPR) m = fmaxf(m, sr[c]);
#pragma unroll
            for (int o = 1; o < TPR; o <<= 1) m = fmaxf(m, __shfl_xor(m, o));
            float s = 0.f;
            for (int c = sub; c < Y; c += TPR) { float e = expf(sr[c] - m); sr[c] = e; s += e; }
#pragma unroll
            for (int o = 1; o < TPR; o <<= 1) s += __shfl_xor(s, o);
            if (sub == 0) invr[row] = 1.f / s;
        }
    }
    __syncthreads();
    for (int idx = t; idx < Rk * Ck; idx += 256) {
        int r = idx / Ck, c = idx - r * Ck;
        float v = (r < X && c < Y) ? sc[r * YRp + c] * invr[r] : 0.f;
        __bf16 h = (__bf16)v;
        Gh[r * Cpad + c] = h; Gl[r * Cpad + c] = (__bf16)(v - (float)h);
    }
    const __bf16* Bb = sg.B + (long)b * sg.bB;
    int bl = t & 63, bc0 = t >> 6;
    for (int n0 = 0; n0 < 768; n0 += 64) {
        __syncthreads();
        for (int c = bc0; c < Ck; c += 4) {
            __bf16 hv = (__bf16)0.f;
            if (c < Y) hv = Bb[(long)c * sg.ldB + n0 + bl];
            Bt[bl * Cpad + c] = hv;
        }
        __syncthreads();
        f32x4 a2[NM] = {};
#pragma unroll
        for (int ks = 0; ks < Ck; ks += 32) {
            bf16x8 bh = *(const bf16x8*)(&Bt[(w * 16 + fr) * Cpad + ks + g * 8]);
#pragma unroll
            for (int m = 0; m < NM; m++) {
                bf16x8 gah = *(const bf16x8*)(&Gh[(m * 16 + fr) * Cpad + ks + g * 8]);
                bf16x8 gal = *(const bf16x8*)(&Gl[(m * 16 + fr) * Cpad + ks + g * 8]);
                a2[m] = MFMA(gah, bh, a2[m], 0, 0, 0);
                a2[m] = MFMA(gal, bh, a2[m], 0, 0, 0);
            }
        }
        float mx = 0.f;
#pragma unroll
        for (int m = 0; m < NM; m++)
#pragma unroll
            for (int r = 0; r < 4; r++) mx = fmaxf(mx, a2[m][r]);
        mx = fmaxf(mx, __shfl_xor(mx, 16));
        mx = fmaxf(mx, __shfl_xor(mx, 32));
        if (g == 0) {
            int col = n0 + w * 16 + fr;
            sg.outF[(long)b * 1536 + col] = mx;
            sg.outH[(long)b * 1536 + col] = (__bf16)mx;
        }
    }
}

__global__ __launch_bounds__(256) void qks_kernel(QSArgs args) {
    __shared__ alignas(16) char POOL[46080];
    int seg = blockIdx.x >> 5, b = blockIdx.x & 31;
    QSSeg sg = args.s[seg];
    int t = threadIdx.x;
    switch (sg.shape) {
        case 1: qks_impl<128, 32>(POOL, sg, b, t); break;
        case 2: qks_impl<128, 24>(POOL, sg, b, t); break;
        case 3: qks_impl<32, 24>(POOL, sg, b, t); break;
        case 4: qks_impl<24, 32>(POOL, sg, b, t); break;
        case 5: qks_impl<32, 128>(POOL, sg, b, t); break;
        default: qks_impl<24, 128>(POOL, sg, b, t); break;
    }
}

// ---------------- logits + log_softmax fused ----------------
__global__ __launch_bounds__(256) void logits_lsm_kernel(
    const float* __restrict__ S, const float* __restrict__ gts,
    const float* __restrict__ V, float* __restrict__ out) {
    int b = blockIdx.x;
    int t = threadIdx.x, i = t >> 6, lane = t & 63;
    int ms[3] = {0, 1 + i, 5 + i};
    float p = 0.f;
    for (int k = 0; k < 3; k++) {
        int m = ms[k];
        const float* Sr = S + (long)m * 49152 + (long)b * 1536;
        const float* gr = gts + ((long)m * 32 + b) * 768;
        const float* Vr = V + k * 768;
        for (int l = lane; l < 768; l += 64) {
            float g = 1.f / (1.f + expf(-gr[l]));
            p += (g * Sr[l] + (1.f - g) * Sr[768 + l]) * Vr[l];
        }
    }
    for (int o = 32; o; o >>= 1) p += __shfl_xor(p, o);
    __shared__ float lgs[4];
    if (lane == 0) lgs[i] = p;
    __syncthreads();
    if (t == 0) {
        float x0 = lgs[0], x1 = lgs[1], x2 = lgs[2], x3 = lgs[3];
        float m = fmaxf(fmaxf(x0, x1), fmaxf(x2, x3));
        float s = expf(x0 - m) + expf(x1 - m) + expf(x2 - m) + expf(x3 - m);
        float ls = m + logf(s);
        out[b * 4 + 0] = x0 - ls; out[b * 4 + 1] = x1 - ls;
        out[b * 4 + 2] = x2 - ls; out[b * 4 + 3] = x3 - ls;
    }
}

// ---------------- host ----------------
extern "C" void kernel_launch(void* const* d_in, const int* in_sizes, int n_in,
                              void* d_out, int out_size, void* d_ws, size_t ws_size,
                              hipStream_t stream) {
    const float* Hp  = (const float*)d_in[0];
    const float* Hq  = (const float*)d_in[1];
    const float* Ha  = (const float*)d_in[2];
    const float* W5  = (const float*)d_in[3];
    const float* W6  = (const float*)d_in[4];
    const float* W7  = (const float*)d_in[5];
    const float* W8  = (const float*)d_in[6];
    const float* b8  = (const float*)d_in[7];
    const float* W9  = (const float*)d_in[8];
    const float* W10 = (const float*)d_in[9];
    const float* W11 = (const float*)d_in[10];
    const float* W12 = (const float*)d_in[11];
    const float* W13 = (const float*)d_in[12];
    const float* W14 = (const float*)d_in[13];
    const float* b14 = (const float*)d_in[14];
    const float* V   = (const float*)d_in[15];
    float* out = (float*)d_out;
    (void)in_sizes; (void)n_in; (void)out_size; (void)ws_size;

    char* base = (char*)d_ws;
    size_t off = 0;
    auto take = [&](size_t bytes) { char* p = base + off; off += (bytes + 15) & ~15UL; return p; };

    __bf16* W5t_h  = (__bf16*)take(1179648);
    __bf16* W5t_l  = (__bf16*)take(1179648);
    __bf16* WsQT_h = (__bf16*)take(2359296);
    __bf16* WsQT_l = (__bf16*)take(2359296);
    __bf16* W6t_h  = (__bf16*)take(3538944);
    __bf16* W6t_l  = (__bf16*)take(3538944);
    __bf16* W1112T = (__bf16*)take(2359296);
    __bf16* W78t   = (__bf16*)take(1179648);
    __bf16* W1314t = (__bf16*)take(2359296);
    float* ra     = (float*)take(12288);
    float* rq     = (float*)take(4096);
    float* amax   = (float*)take(524288);
    int*   topidx = (int*)take(256);
    __bf16* Ha_h  = (__bf16*)take(4718592);
    __bf16* Ha_l  = (__bf16*)take(4718592);
    __bf16* Hq_h  = (__bf16*)take(1572864);
    __bf16* Hq_l  = (__bf16*)take(1572864);
    __bf16* Hps_h = (__bf16*)take(6291456);
    __bf16* Hps_l = (__bf16*)take(6291456);
    __bf16* C1_h  = (__bf16*)take(4718592);
    __bf16* C1_l  = (__bf16*)take(4718592);
    __bf16* HqS_h = (__bf16*)take(3145728);
    __bf16* HqS_l = (__bf16*)take(3145728);
    __bf16* c1_h  = (__bf16*)take(6291456);
    __bf16* c1_l  = (__bf16*)take(6291456);
    __bf16* c4_h  = (__bf16*)take(4718592);
    __bf16* c4_l  = (__bf16*)take(4718592);
    __bf16* Ho_h  = (__bf16*)take(4718592);
    __bf16* Ho_l  = (__bf16*)take(4718592);
    __bf16* hats_h = (__bf16*)take(14155776);
    __bf16* hats_l = (__bf16*)take(14155776);
    __bf16* bar_h  = (__bf16*)take(4718592);
    __bf16* HqS2_bf   = (__bf16*)take(3145728);
    __bf16* HpsW12_bf = (__bf16*)take(6291456);
    __bf16* HoW11_bf  = (__bf16*)take(4718592);
    __bf16* S_h    = (__bf16*)take(884736);
    float* bar  = (float*)take(9437184);
    float* S    = (float*)take(1769472);
    float* gts  = (float*)take(884736);

    dim3 blk(256);

    prep_kernel<<<6336, blk, 0, stream>>>(W5, W6, W7, W8, W9, W10, W11, W12, W13, W14,
                                          W5t_h, W5t_l, WsQT_h, WsQT_l, W6t_h, W6t_l,
                                          W1112T, W78t, W1314t);
    cvt2n_kernel<<<4096, blk, 0, stream>>>(Ha, Ha_h, Ha_l, ra, Hq, Hq_h, Hq_l, rq);

    simmax_kernel<<<1024, blk, 0, stream>>>(Hp, Ha_h, Ha_l, Hq_h, Hq_l, ra, rq, amax);
    score_top2_kernel<<<32, dim3(64), 0, stream>>>(amax, topidx);
    gather_kernel<<<12288, blk, 0, stream>>>(Hp, topidx, Hps_h, Hps_l);

    // batched projection GEMMs (64x64 tiles, full grids)
    {
        PXArgs pa{};
        pa.s[0] = { Ha_h, Ha_l, W5t_h, W5t_l, C1_h, C1_l, 3072, 768, 48 };
        pa.s[1] = { Hq_h, Hq_l, WsQT_h, WsQT_l, HqS_h, HqS_l, 1024, 1536, 16 };
        pa.s[2] = { Hps_h, Hps_l, WsQT_h, WsQT_l, c1_h, c1_l, 4096, 768, 64 };
        projx_kernel<<<1728, blk, 0, stream>>>(pa);
    }
    {
        PPArgs pa{};
        pa.s[0] = { Hq_h, W1112T, HqS2_bf, 1024, 1536, 16 };
        pa.s[1] = { Hps_h, W1112T + (long)768 * 768, HpsW12_bf, 4096, 768, 64 };
        projp_kernel<<<1152, blk, 0, stream>>>(pa);
    }

    // stage-2 fused QK + hats
    {
        QHArgs qa{}; int si = 0;
        for (int i = 0; i < 4; i++) {
            int jj = 0;
            for (int j = 0; j < 4; j++) {
                if (j == i) continue;
                QHSeg& s = qa.s[si];
                s.GLh = C1_h + (long)i * 24 * 768; s.GLl = C1_l + (long)i * 24 * 768;
                s.HYh = Ha_h + (long)j * 24 * 768; s.HYl = Ha_l + (long)j * 24 * 768;
                s.outH = hats_h + (long)i * 24 * 2304 + jj * 768;
                s.outL = hats_l + (long)i * 24 * 2304 + jj * 768;
                s.glB = 73728; s.hyB = 73728; s.oB = 221184;
                si++; jj++;
            }
        }
        qkh_kernel<<<12 * 32, blk, 0, stream>>>(qa);
    }
    // bar = hats@W6; fused gate GEMM -> Ho; c4; HoW11
    mgemm3_kernel<1><<<dim3(48, 12), blk, 0, stream>>>(hats_h, hats_l, 2304, 3072, W6t_h, W6t_l, bar, 768, bar_h, nullptr);
    mgemm_gate_kernel<<<dim3(48, 12), blk, 0, stream>>>(bar_h, W78t, b8, Ha, bar, Ho_h, Ho_l);
    mgemm3_kernel<2><<<dim3(48, 12), blk, 0, stream>>>(Ho_h, Ho_l, 768, 3072, WsQT_h + (long)768 * 768, WsQT_l + (long)768 * 768, nullptr, 768, c4_h, c4_l);
    mgemm_kernel<0, 1><<<dim3(48, 12), blk, 0, stream>>>(Ho_h, 768, 3072, W1112T, nullptr, nullptr, 768, HoW11_bf);

    // match: fused QK + softmax + colmax S (18 segs)
    {
        QSArgs qa{};
        auto set = [&](int k, const __bf16* GLh, const __bf16* GLl, long glB, int ldGL,
                       const __bf16* HYh, const __bf16* HYl, long hyB, int ldHY,
                       const __bf16* B, long bB, int ldB,
                       float* oF, __bf16* oH, int shape) {
            QSSeg& s = qa.s[k];
            s.GLh = GLh; s.GLl = GLl; s.HYh = HYh; s.HYl = HYl; s.B = B;
            s.outF = oF; s.outH = oH;
            s.glB = glB; s.hyB = hyB; s.bB = bB;
            s.ldGL = ldGL; s.ldHY = ldHY; s.ldB = ldB; s.shape = shape;
        };
        set(0, c1_h, c1_l, 98304, 768, Hq_h, Hq_l, 24576, 768,
            HqS2_bf, 49152, 1536, S, S_h, 1);
        for (int i = 0; i < 4; i++) {
            set(1 + i, c1_h, c1_l, 98304, 768,
                Ho_h + (long)i * 24 * 768, Ho_l + (long)i * 24 * 768, 73728, 768,
                HoW11_bf + (long)i * 24 * 768, 73728, 768,
                S + (long)(1 + i) * 49152, S_h + (long)(1 + i) * 49152, 2);
            set(5 + i, HqS_h, HqS_l, 49152, 1536,
                Ho_h + (long)i * 24 * 768, Ho_l + (long)i * 24 * 768, 73728, 768,
                HoW11_bf + (long)i * 24 * 768, 73728, 768,
                S + (long)(5 + i) * 49152, S_h + (long)(5 + i) * 49152, 3);
            set(9 + i, c4_h + (long)i * 24 * 768, c4_l + (long)i * 24 * 768, 73728, 768,
                Hq_h, Hq_l, 24576, 768,
                HqS2_bf + 768, 49152, 1536,
                S + (long)(5 + i) * 49152 + 768, S_h + (long)(5 + i) * 49152 + 768, 4);
        }
        set(13, HqS_h + 768, HqS_l + 768, 49152, 1536, Hps_h, Hps_l, 98304, 768,
            HpsW12_bf, 98304, 768, S + 768, S_h + 768, 5);
        for (int i = 0; i < 4; i++)
            set(14 + i, c4_h + (long)i * 24 * 768, c4_l + (long)i * 24 * 768, 73728, 768,
                Hps_h, Hps_l, 98304, 768,
                HpsW12_bf, 98304, 768,
                S + (long)(1 + i) * 49152 + 768, S_h + (long)(1 + i) * 49152 + 768, 6);
        qks_kernel<<<18 * 32, blk, 0, stream>>>(qa);
    }

    // gating: gts = [Sxy|Syx] @ [W13;W14] + b14
    mgemm_kernel<1, 0><<<dim3(5, 12), blk, 0, stream>>>(S_h, 1536, 288, W1314t, b14, gts, 768, nullptr);

    logits_lsm_kernel<<<32, blk, 0, stream>>>(S, gts, V, out);
}